// Round 1
// baseline (3770.638 us; speedup 1.0000x reference)
//
#include <hip/hip_runtime.h>

#define EMBED_DIM 64
#define LANES 64

// ---------- init: x = concat(user_emb, item_emb), vectorized float4 ----------
__global__ void init_x_kernel(const float* __restrict__ ue, const float* __restrict__ ie,
                              float* __restrict__ x, int nu_elems, int total_elems) {
    int i = blockIdx.x * blockDim.x + threadIdx.x;
    int stride = gridDim.x * blockDim.x;
    int n4 = total_elems >> 2;
    int nu4 = nu_elems >> 2;
    const float4* ue4 = reinterpret_cast<const float4*>(ue);
    const float4* ie4 = reinterpret_cast<const float4*>(ie);
    float4* x4 = reinterpret_cast<float4*>(x);
    for (; i < n4; i += stride) {
        x4[i] = (i < nu4) ? ue4[i] : ie4[i - nu4];
    }
}

// ---------- zero a float buffer (float4) ----------
__global__ void zero_kernel(float* __restrict__ p, int n4) {
    int i = blockIdx.x * blockDim.x + threadIdx.x;
    int stride = gridDim.x * blockDim.x;
    float4 z = make_float4(0.f, 0.f, 0.f, 0.f);
    float4* p4 = reinterpret_cast<float4*>(p);
    for (; i < n4; i += stride) p4[i] = z;
}

// ---------- batch accumulator init: uacc[b] = user_emb[uid[b]], iacc[b] = item_emb[iid[b]] ----------
__global__ void init_bacc_kernel(const float* __restrict__ ue, const float* __restrict__ ie,
                                 const int* __restrict__ uids, const int* __restrict__ iids,
                                 float* __restrict__ uacc, float* __restrict__ iacc, int batch) {
    int t = blockIdx.x * blockDim.x + threadIdx.x;
    if (t >= batch * EMBED_DIM) return;
    int b = t >> 6;
    int d = t & 63;
    uacc[t] = ue[(long)uids[b] * EMBED_DIM + d];
    iacc[t] = ie[(long)iids[b] * EMBED_DIM + d];
}

// ---------- SpMM scatter: y[row] += val * x[col], one wave handles 64 edges at a time ----------
__global__ void spmm_scatter_kernel(const int* __restrict__ rows, const int* __restrict__ cols,
                                    const float* __restrict__ vals, const float* __restrict__ x,
                                    float* __restrict__ y, int nnz) {
    int lane = threadIdx.x & 63;
    int wave = (blockIdx.x * blockDim.x + threadIdx.x) >> 6;
    int nwaves = (gridDim.x * blockDim.x) >> 6;
    int nchunks = (nnz + 63) >> 6;
    for (int chunk = wave; chunk < nchunks; chunk += nwaves) {
        int base = chunk << 6;
        int e = base + lane;
        int r = 0, c = 0;
        float v = 0.f;
        if (e < nnz) {
            r = rows[e];
            c = cols[e];
            v = vals[e];
        }
        int cnt = min(64, nnz - base);
        for (int j = 0; j < cnt; ++j) {
            int   rj = __shfl(r, j);
            int   cj = __shfl(c, j);
            float vj = __shfl(v, j);
            float contrib = vj * x[(long)cj * EMBED_DIM + lane];
            atomicAdd(&y[(long)rj * EMBED_DIM + lane], contrib);
        }
    }
}

// ---------- per-layer batch accumulate: uacc[b] += y[uid[b]], iacc[b] += y[NU + iid[b]] ----------
__global__ void bacc_add_kernel(const float* __restrict__ y,
                                const int* __restrict__ uids, const int* __restrict__ iids,
                                float* __restrict__ uacc, float* __restrict__ iacc,
                                int batch, int num_users) {
    int t = blockIdx.x * blockDim.x + threadIdx.x;
    if (t >= batch * EMBED_DIM) return;
    int b = t >> 6;
    int d = t & 63;
    uacc[t] += y[(long)uids[b] * EMBED_DIM + d];
    iacc[t] += y[((long)num_users + iids[b]) * EMBED_DIM + d];
}

// ---------- scoring: one wave per batch element, shuffle-reduce dot ----------
__global__ void score_kernel(const float* __restrict__ uacc, const float* __restrict__ iacc,
                             float* __restrict__ out, int batch) {
    int lane = threadIdx.x & 63;
    int w = (blockIdx.x * blockDim.x + threadIdx.x) >> 6;
    if (w >= batch) return;
    float p = uacc[(long)w * EMBED_DIM + lane] * iacc[(long)w * EMBED_DIM + lane];
    #pragma unroll
    for (int off = 32; off > 0; off >>= 1) p += __shfl_down(p, off);
    if (lane == 0) out[w] = p * (1.0f / 16.0f);  // (acc/4)·(acc/4)
}

extern "C" void kernel_launch(void* const* d_in, const int* in_sizes, int n_in,
                              void* d_out, int out_size, void* d_ws, size_t ws_size,
                              hipStream_t stream) {
    const float* user_emb = (const float*)d_in[0];
    const float* item_emb = (const float*)d_in[1];
    const int*   adj_rows = (const int*)d_in[2];
    const int*   adj_cols = (const int*)d_in[3];
    const float* adj_vals = (const float*)d_in[4];
    const int*   user_ids = (const int*)d_in[5];
    const int*   item_ids = (const int*)d_in[6];
    float* out = (float*)d_out;

    const int num_users = in_sizes[0] / EMBED_DIM;   // 200000
    const int num_items = in_sizes[1] / EMBED_DIM;   // 100000
    const int n_nodes   = num_users + num_items;     // 300000
    const int nnz       = in_sizes[2];               // 6000000
    const int batch     = in_sizes[5];               // 16384

    const long node_elems = (long)n_nodes * EMBED_DIM;    // 19.2M floats
    const long bacc_elems = (long)batch * EMBED_DIM;      // 1.05M floats

    // workspace layout (floats)
    float* xbuf = (float*)d_ws;                    // node_elems
    float* ybuf = xbuf + node_elems;               // node_elems
    float* uacc = ybuf + node_elems;               // bacc_elems
    float* iacc = uacc + bacc_elems;               // bacc_elems

    // 1. init x = concat(user_emb, item_emb)
    {
        int n4 = (int)(node_elems >> 2);
        int blocks = min((n4 + 255) / 256, 2048);
        init_x_kernel<<<blocks, 256, 0, stream>>>(user_emb, item_emb, xbuf,
                                                  num_users * EMBED_DIM, (int)node_elems);
    }
    // 2. init batch accumulators (layer-0 term)
    {
        int threads = (int)bacc_elems;
        int blocks = (threads + 255) / 256;
        init_bacc_kernel<<<blocks, 256, 0, stream>>>(user_emb, item_emb, user_ids, item_ids,
                                                     uacc, iacc, batch);
    }

    float* x = xbuf;
    float* y = ybuf;
    for (int layer = 0; layer < 3; ++layer) {
        // zero y
        {
            int n4 = (int)(node_elems >> 2);
            int blocks = min((n4 + 255) / 256, 2048);
            zero_kernel<<<blocks, 256, 0, stream>>>(y, n4);
        }
        // scatter SpMM: y = A * x
        {
            int blocks = 2048;  // 8192 waves -> 32 waves/CU
            spmm_scatter_kernel<<<blocks, 256, 0, stream>>>(adj_rows, adj_cols, adj_vals,
                                                            x, y, nnz);
        }
        // accumulate batch rows
        {
            int threads = (int)bacc_elems;
            int blocks = (threads + 255) / 256;
            bacc_add_kernel<<<blocks, 256, 0, stream>>>(y, user_ids, item_ids,
                                                        uacc, iacc, batch, num_users);
        }
        // swap
        float* t = x; x = y; y = t;
    }

    // 3. score
    {
        int waves = batch;
        int blocks = (waves * 64 + 255) / 256;
        score_kernel<<<blocks, 256, 0, stream>>>(uacc, iacc, out, batch);
    }
}

// Round 2
// 1243.297 us; speedup vs baseline: 3.0328x; 3.0328x over previous
//
#include <hip/hip_runtime.h>

#define EMBED_DIM 64
#define SCAN_CHUNK 1024   // elements per scan block (256 threads x 4)

// ---------- init: x = concat(user_emb, item_emb), vectorized float4 ----------
__global__ void init_x_kernel(const float* __restrict__ ue, const float* __restrict__ ie,
                              float* __restrict__ x, int nu_elems, int total_elems) {
    int i = blockIdx.x * blockDim.x + threadIdx.x;
    int stride = gridDim.x * blockDim.x;
    int n4 = total_elems >> 2;
    int nu4 = nu_elems >> 2;
    const float4* ue4 = reinterpret_cast<const float4*>(ue);
    const float4* ie4 = reinterpret_cast<const float4*>(ie);
    float4* x4 = reinterpret_cast<float4*>(x);
    for (; i < n4; i += stride) {
        x4[i] = (i < nu4) ? ue4[i] : ie4[i - nu4];
    }
}

// ---------- histogram of rows ----------
__global__ void hist_kernel(const int* __restrict__ rows, int* __restrict__ counts, int nnz) {
    int i = blockIdx.x * blockDim.x + threadIdx.x;
    int stride = gridDim.x * blockDim.x;
    for (; i < nnz; i += stride) atomicAdd(&counts[rows[i]], 1);
}

// ---------- scan phase 1: per-block sums ----------
__global__ void scan_phase1(const int* __restrict__ counts, int* __restrict__ bsum, int n) {
    __shared__ int wsum[4];
    int t = threadIdx.x;
    int b = blockIdx.x;
    int i0 = b * SCAN_CHUNK + t * 4;
    int s = 0;
    #pragma unroll
    for (int k = 0; k < 4; ++k) { int i = i0 + k; if (i < n) s += counts[i]; }
    #pragma unroll
    for (int off = 1; off < 64; off <<= 1) s += __shfl_xor(s, off);
    if ((t & 63) == 0) wsum[t >> 6] = s;
    __syncthreads();
    if (t == 0) bsum[b] = wsum[0] + wsum[1] + wsum[2] + wsum[3];
}

// ---------- scan phase 2: single-block scan of block sums (nb <= 512) ----------
__global__ void scan_phase2(const int* __restrict__ bsum, int* __restrict__ boff, int nb) {
    __shared__ int lds[512];
    int t = threadIdx.x;
    lds[t] = (t < nb) ? bsum[t] : 0;
    __syncthreads();
    for (int off = 1; off < 512; off <<= 1) {
        int v = (t >= off) ? lds[t - off] : 0;
        __syncthreads();
        lds[t] += v;
        __syncthreads();
    }
    if (t < nb) boff[t] = (t == 0) ? 0 : lds[t - 1];
}

// ---------- scan phase 3: write exclusive prefix (row_ptr) + cursor copy ----------
__global__ void scan_phase3(const int* __restrict__ counts, const int* __restrict__ boff,
                            int* __restrict__ row_ptr, int* __restrict__ cursor,
                            int n, int nnz_total) {
    __shared__ int wexcl[4];
    int t = threadIdx.x;
    int lane = t & 63;
    int w = t >> 6;
    int b = blockIdx.x;
    int i0 = b * SCAN_CHUNK + t * 4;
    int c[4];
    #pragma unroll
    for (int k = 0; k < 4; ++k) { int i = i0 + k; c[k] = (i < n) ? counts[i] : 0; }
    int s = c[0] + c[1] + c[2] + c[3];
    int incl = s;
    #pragma unroll
    for (int off = 1; off < 64; off <<= 1) {
        int u = __shfl_up(incl, off);
        if (lane >= off) incl += u;
    }
    if (lane == 63) wexcl[w] = incl;
    __syncthreads();
    int wbase = 0;
    for (int ww = 0; ww < w; ++ww) wbase += wexcl[ww];
    int run = incl - s + wbase + boff[b];
    #pragma unroll
    for (int k = 0; k < 4; ++k) {
        int i = i0 + k;
        if (i < n) { row_ptr[i] = run; cursor[i] = run; run += c[k]; }
    }
    if (b == 0 && t == 0) row_ptr[n] = nnz_total;
}

// ---------- permute edges into row-sorted (col, val) pairs ----------
__global__ void permute_kernel(const int* __restrict__ rows, const int* __restrict__ cols,
                               const float* __restrict__ vals, int* __restrict__ cursor,
                               int2* __restrict__ perm, int nnz) {
    int i = blockIdx.x * blockDim.x + threadIdx.x;
    int stride = gridDim.x * blockDim.x;
    for (; i < nnz; i += stride) {
        int r = rows[i];
        int p = atomicAdd(&cursor[r], 1);
        perm[p] = make_int2(cols[i], __float_as_int(vals[i]));
    }
}

// ---------- batch accumulator init ----------
__global__ void init_bacc_kernel(const float* __restrict__ ue, const float* __restrict__ ie,
                                 const int* __restrict__ uids, const int* __restrict__ iids,
                                 float* __restrict__ uacc, float* __restrict__ iacc, int batch) {
    int t = blockIdx.x * blockDim.x + threadIdx.x;
    if (t >= batch * EMBED_DIM) return;
    int b = t >> 6;
    int d = t & 63;
    uacc[t] = ue[(long)uids[b] * EMBED_DIM + d];
    iacc[t] = ie[(long)iids[b] * EMBED_DIM + d];
}

// ---------- CSR gather SpMM: one wave per row, lane = dim ----------
__global__ __launch_bounds__(256) void spmm_csr_kernel(
    const int* __restrict__ row_ptr, const int2* __restrict__ perm,
    const float* __restrict__ x, float* __restrict__ y, int n_nodes) {
    int lane = threadIdx.x & 63;
    int row = (blockIdx.x * blockDim.x + threadIdx.x) >> 6;
    if (row >= n_nodes) return;
    int start = row_ptr[row];
    int end   = row_ptr[row + 1];
    float acc = 0.f;
    for (int base = start; base < end; base += 64) {
        int cnt = min(64, end - base);
        int2 p = make_int2(0, 0);
        if (lane < cnt) p = perm[base + lane];
        int j = 0;
        for (; j + 4 <= cnt; j += 4) {
            int   c0 = __shfl(p.x, j),     c1 = __shfl(p.x, j + 1);
            int   c2 = __shfl(p.x, j + 2), c3 = __shfl(p.x, j + 3);
            float v0 = __int_as_float(__shfl(p.y, j));
            float v1 = __int_as_float(__shfl(p.y, j + 1));
            float v2 = __int_as_float(__shfl(p.y, j + 2));
            float v3 = __int_as_float(__shfl(p.y, j + 3));
            float x0 = x[(long)c0 * EMBED_DIM + lane];
            float x1 = x[(long)c1 * EMBED_DIM + lane];
            float x2 = x[(long)c2 * EMBED_DIM + lane];
            float x3 = x[(long)c3 * EMBED_DIM + lane];
            acc = fmaf(v0, x0, acc);
            acc = fmaf(v1, x1, acc);
            acc = fmaf(v2, x2, acc);
            acc = fmaf(v3, x3, acc);
        }
        for (; j < cnt; ++j) {
            int   cj = __shfl(p.x, j);
            float vj = __int_as_float(__shfl(p.y, j));
            acc = fmaf(vj, x[(long)cj * EMBED_DIM + lane], acc);
        }
    }
    y[(long)row * EMBED_DIM + lane] = acc;
}

// ---------- per-layer batch accumulate ----------
__global__ void bacc_add_kernel(const float* __restrict__ y,
                                const int* __restrict__ uids, const int* __restrict__ iids,
                                float* __restrict__ uacc, float* __restrict__ iacc,
                                int batch, int num_users) {
    int t = blockIdx.x * blockDim.x + threadIdx.x;
    if (t >= batch * EMBED_DIM) return;
    int b = t >> 6;
    int d = t & 63;
    uacc[t] += y[(long)uids[b] * EMBED_DIM + d];
    iacc[t] += y[((long)num_users + iids[b]) * EMBED_DIM + d];
}

// ---------- scoring ----------
__global__ void score_kernel(const float* __restrict__ uacc, const float* __restrict__ iacc,
                             float* __restrict__ out, int batch) {
    int lane = threadIdx.x & 63;
    int w = (blockIdx.x * blockDim.x + threadIdx.x) >> 6;
    if (w >= batch) return;
    float p = uacc[(long)w * EMBED_DIM + lane] * iacc[(long)w * EMBED_DIM + lane];
    #pragma unroll
    for (int off = 32; off > 0; off >>= 1) p += __shfl_down(p, off);
    if (lane == 0) out[w] = p * (1.0f / 16.0f);  // (acc/4)·(acc/4)
}

extern "C" void kernel_launch(void* const* d_in, const int* in_sizes, int n_in,
                              void* d_out, int out_size, void* d_ws, size_t ws_size,
                              hipStream_t stream) {
    const float* user_emb = (const float*)d_in[0];
    const float* item_emb = (const float*)d_in[1];
    const int*   adj_rows = (const int*)d_in[2];
    const int*   adj_cols = (const int*)d_in[3];
    const float* adj_vals = (const float*)d_in[4];
    const int*   user_ids = (const int*)d_in[5];
    const int*   item_ids = (const int*)d_in[6];
    float* out = (float*)d_out;

    const int num_users = in_sizes[0] / EMBED_DIM;   // 200000
    const int num_items = in_sizes[1] / EMBED_DIM;   // 100000
    const int n_nodes   = num_users + num_items;     // 300000
    const int nnz       = in_sizes[2];               // 6000000
    const int batch     = in_sizes[5];               // 16384

    const long node_elems = (long)n_nodes * EMBED_DIM;    // 19.2M floats
    const long bacc_elems = (long)batch * EMBED_DIM;      // 1.05M floats

    // ---- workspace layout ----
    char* wp = (char*)d_ws;
    float* xbuf = (float*)wp;            wp += node_elems * sizeof(float);
    float* ybuf = (float*)wp;            wp += node_elems * sizeof(float);
    float* uacc = (float*)wp;            wp += bacc_elems * sizeof(float);
    float* iacc = (float*)wp;            wp += bacc_elems * sizeof(float);
    int*   counts  = (int*)wp;           wp += (size_t)n_nodes * sizeof(int);
    int*   row_ptr = (int*)wp;           wp += (size_t)(n_nodes + 1) * sizeof(int);
    int*   cursor  = (int*)wp;           wp += (size_t)n_nodes * sizeof(int);
    int*   bsum    = (int*)wp;           wp += 512 * sizeof(int);
    int*   boff    = (int*)wp;           wp += 512 * sizeof(int);
    wp = (char*)(((uintptr_t)wp + 15) & ~(uintptr_t)15);
    int2*  perm    = (int2*)wp;          wp += (size_t)nnz * sizeof(int2);

    const int nscan_blocks = (n_nodes + SCAN_CHUNK - 1) / SCAN_CHUNK;  // 293

    // ---- CSR build ----
    hipMemsetAsync(counts, 0, (size_t)n_nodes * sizeof(int), stream);
    hist_kernel<<<2048, 256, 0, stream>>>(adj_rows, counts, nnz);
    scan_phase1<<<nscan_blocks, 256, 0, stream>>>(counts, bsum, n_nodes);
    scan_phase2<<<1, 512, 0, stream>>>(bsum, boff, nscan_blocks);
    scan_phase3<<<nscan_blocks, 256, 0, stream>>>(counts, boff, row_ptr, cursor, n_nodes, nnz);
    permute_kernel<<<2048, 256, 0, stream>>>(adj_rows, adj_cols, adj_vals, cursor, perm, nnz);

    // ---- x init + batch accumulator init ----
    {
        int n4 = (int)(node_elems >> 2);
        int blocks = min((n4 + 255) / 256, 2048);
        init_x_kernel<<<blocks, 256, 0, stream>>>(user_emb, item_emb, xbuf,
                                                  num_users * EMBED_DIM, (int)node_elems);
    }
    {
        int blocks = ((int)bacc_elems + 255) / 256;
        init_bacc_kernel<<<blocks, 256, 0, stream>>>(user_emb, item_emb, user_ids, item_ids,
                                                     uacc, iacc, batch);
    }

    // ---- 3 propagation layers ----
    float* x = xbuf;
    float* y = ybuf;
    for (int layer = 0; layer < 3; ++layer) {
        int blocks = ((n_nodes * 64) + 255) / 256;   // one wave per row
        spmm_csr_kernel<<<blocks, 256, 0, stream>>>(row_ptr, perm, x, y, n_nodes);
        int bblocks = ((int)bacc_elems + 255) / 256;
        bacc_add_kernel<<<bblocks, 256, 0, stream>>>(y, user_ids, item_ids,
                                                     uacc, iacc, batch, num_users);
        float* t = x; x = y; y = t;
    }

    // ---- score ----
    {
        int blocks = (batch * 64 + 255) / 256;
        score_kernel<<<blocks, 256, 0, stream>>>(uacc, iacc, out, batch);
    }
}

// Round 3
// 1176.688 us; speedup vs baseline: 3.2045x; 1.0566x over previous
//
#include <hip/hip_runtime.h>

#define EMBED_DIM 64
#define SCAN_CHUNK 1024   // elements per scan block (256 threads x 4)

// ---------- histogram of rows, keeping per-edge rank (atomic return) ----------
__global__ void hist_rank_kernel(const int* __restrict__ rows, int* __restrict__ counts,
                                 int* __restrict__ rank, int nnz) {
    int i = blockIdx.x * blockDim.x + threadIdx.x;
    int stride = gridDim.x * blockDim.x;
    for (; i < nnz; i += stride) {
        rank[i] = atomicAdd(&counts[rows[i]], 1);
    }
}

// ---------- scan phase 1: per-block sums ----------
__global__ void scan_phase1(const int* __restrict__ counts, int* __restrict__ bsum, int n) {
    __shared__ int wsum[4];
    int t = threadIdx.x;
    int b = blockIdx.x;
    int i0 = b * SCAN_CHUNK + t * 4;
    int s = 0;
    #pragma unroll
    for (int k = 0; k < 4; ++k) { int i = i0 + k; if (i < n) s += counts[i]; }
    #pragma unroll
    for (int off = 1; off < 64; off <<= 1) s += __shfl_xor(s, off);
    if ((t & 63) == 0) wsum[t >> 6] = s;
    __syncthreads();
    if (t == 0) bsum[b] = wsum[0] + wsum[1] + wsum[2] + wsum[3];
}

// ---------- scan phase 2: single-block scan of block sums (nb <= 512) ----------
__global__ void scan_phase2(const int* __restrict__ bsum, int* __restrict__ boff, int nb) {
    __shared__ int lds[512];
    int t = threadIdx.x;
    lds[t] = (t < nb) ? bsum[t] : 0;
    __syncthreads();
    for (int off = 1; off < 512; off <<= 1) {
        int v = (t >= off) ? lds[t - off] : 0;
        __syncthreads();
        lds[t] += v;
        __syncthreads();
    }
    if (t < nb) boff[t] = (t == 0) ? 0 : lds[t - 1];
}

// ---------- scan phase 3: write exclusive prefix (row_ptr) ----------
__global__ void scan_phase3(const int* __restrict__ counts, const int* __restrict__ boff,
                            int* __restrict__ row_ptr, int n, int nnz_total) {
    __shared__ int wexcl[4];
    int t = threadIdx.x;
    int lane = t & 63;
    int w = t >> 6;
    int b = blockIdx.x;
    int i0 = b * SCAN_CHUNK + t * 4;
    int c[4];
    #pragma unroll
    for (int k = 0; k < 4; ++k) { int i = i0 + k; c[k] = (i < n) ? counts[i] : 0; }
    int s = c[0] + c[1] + c[2] + c[3];
    int incl = s;
    #pragma unroll
    for (int off = 1; off < 64; off <<= 1) {
        int u = __shfl_up(incl, off);
        if (lane >= off) incl += u;
    }
    if (lane == 63) wexcl[w] = incl;
    __syncthreads();
    int wbase = 0;
    for (int ww = 0; ww < w; ++ww) wbase += wexcl[ww];
    int run = incl - s + wbase + boff[b];
    #pragma unroll
    for (int k = 0; k < 4; ++k) {
        int i = i0 + k;
        if (i < n) { row_ptr[i] = run; run += c[k]; }
    }
    if (b == 0 && t == 0) row_ptr[n] = nnz_total;
}

// ---------- atomic-free permute: position = row_ptr[row] + rank ----------
__global__ void permute_kernel(const int* __restrict__ rows, const int* __restrict__ cols,
                               const float* __restrict__ vals,
                               const int* __restrict__ row_ptr, const int* __restrict__ rank,
                               int2* __restrict__ perm, int nnz) {
    int i = blockIdx.x * blockDim.x + threadIdx.x;
    int stride = gridDim.x * blockDim.x;
    for (; i < nnz; i += stride) {
        int p = row_ptr[rows[i]] + rank[i];
        perm[p] = make_int2(cols[i], __float_as_int(vals[i]));
    }
}

// ---------- batch accumulator init (float4) ----------
__global__ void init_bacc_kernel(const float* __restrict__ ue, const float* __restrict__ ie,
                                 const int* __restrict__ uids, const int* __restrict__ iids,
                                 float* __restrict__ uacc, float* __restrict__ iacc, int batch) {
    int t = blockIdx.x * blockDim.x + threadIdx.x;
    if (t >= batch * 16) return;
    int b = t >> 4;
    int q = t & 15;
    const float4* ue4 = (const float4*)ue;
    const float4* ie4 = (const float4*)ie;
    ((float4*)uacc)[t] = ue4[(long)uids[b] * 16 + q];
    ((float4*)iacc)[t] = ie4[(long)iids[b] * 16 + q];
}

// ---------- CSR gather SpMM: one wave per row, 4 edges x float4 per iteration ----------
// lane = (edge slot: lane>>4, dim quad: lane&15)
// Column c reads from xu if c < nu else from xi_off (xi_off pre-shifted so
// xi_off + c*64 is correct for c >= nu). For inner layers pass (x, x, 0-equivalent).
__global__ __launch_bounds__(256) void spmm_csr_kernel(
    const int* __restrict__ row_ptr, const int2* __restrict__ perm,
    const float* __restrict__ xu, const float* __restrict__ xi_off, int nu,
    float* __restrict__ y, int n_nodes) {
    int lane = threadIdx.x & 63;
    int row = (blockIdx.x * blockDim.x + threadIdx.x) >> 6;
    if (row >= n_nodes) return;
    int start = row_ptr[row];
    int end   = row_ptr[row + 1];
    int sub  = lane >> 4;    // edge slot 0..3
    int dimq = lane & 15;    // float4 index within the 64-dim row
    float4 acc = make_float4(0.f, 0.f, 0.f, 0.f);
    for (int base = start; base < end; base += 4) {
        int e = base + sub;
        int2 p = make_int2(0, 0);               // val=0 -> contributes nothing
        if (e < end) p = perm[e];
        float v = __int_as_float(p.y);
        const float* xrow = (p.x < nu) ? (xu + (long)p.x * EMBED_DIM)
                                       : (xi_off + (long)p.x * EMBED_DIM);
        float4 xv = reinterpret_cast<const float4*>(xrow)[dimq];
        acc.x = fmaf(v, xv.x, acc.x);
        acc.y = fmaf(v, xv.y, acc.y);
        acc.z = fmaf(v, xv.z, acc.z);
        acc.w = fmaf(v, xv.w, acc.w);
    }
    // reduce across the 4 edge slots (xor lane bits 4,5)
    #pragma unroll
    for (int off = 16; off < 64; off <<= 1) {
        acc.x += __shfl_xor(acc.x, off);
        acc.y += __shfl_xor(acc.y, off);
        acc.z += __shfl_xor(acc.z, off);
        acc.w += __shfl_xor(acc.w, off);
    }
    if (sub == 0) {
        reinterpret_cast<float4*>(y + (long)row * EMBED_DIM)[dimq] = acc;
    }
}

// ---------- per-layer batch accumulate (float4) ----------
__global__ void bacc_add_kernel(const float* __restrict__ y,
                                const int* __restrict__ uids, const int* __restrict__ iids,
                                float* __restrict__ uacc, float* __restrict__ iacc,
                                int batch, int num_users) {
    int t = blockIdx.x * blockDim.x + threadIdx.x;
    if (t >= batch * 16) return;
    int b = t >> 4;
    int q = t & 15;
    const float4* y4 = (const float4*)y;
    float4 u = y4[(long)uids[b] * 16 + q];
    float4 v = y4[((long)num_users + iids[b]) * 16 + q];
    float4* ua = (float4*)uacc;
    float4* ia = (float4*)iacc;
    float4 a = ua[t];
    a.x += u.x; a.y += u.y; a.z += u.z; a.w += u.w;
    ua[t] = a;
    float4 c = ia[t];
    c.x += v.x; c.y += v.y; c.z += v.z; c.w += v.w;
    ia[t] = c;
}

// ---------- scoring ----------
__global__ void score_kernel(const float* __restrict__ uacc, const float* __restrict__ iacc,
                             float* __restrict__ out, int batch) {
    int lane = threadIdx.x & 63;
    int w = (blockIdx.x * blockDim.x + threadIdx.x) >> 6;
    if (w >= batch) return;
    float p = uacc[(long)w * EMBED_DIM + lane] * iacc[(long)w * EMBED_DIM + lane];
    #pragma unroll
    for (int off = 32; off > 0; off >>= 1) p += __shfl_down(p, off);
    if (lane == 0) out[w] = p * (1.0f / 16.0f);  // (acc/4)·(acc/4)
}

extern "C" void kernel_launch(void* const* d_in, const int* in_sizes, int n_in,
                              void* d_out, int out_size, void* d_ws, size_t ws_size,
                              hipStream_t stream) {
    const float* user_emb = (const float*)d_in[0];
    const float* item_emb = (const float*)d_in[1];
    const int*   adj_rows = (const int*)d_in[2];
    const int*   adj_cols = (const int*)d_in[3];
    const float* adj_vals = (const float*)d_in[4];
    const int*   user_ids = (const int*)d_in[5];
    const int*   item_ids = (const int*)d_in[6];
    float* out = (float*)d_out;

    const int num_users = in_sizes[0] / EMBED_DIM;   // 200000
    const int num_items = in_sizes[1] / EMBED_DIM;   // 100000
    const int n_nodes   = num_users + num_items;     // 300000
    const int nnz       = in_sizes[2];               // 6000000
    const int batch     = in_sizes[5];               // 16384

    const long node_elems = (long)n_nodes * EMBED_DIM;    // 19.2M floats
    const long bacc_elems = (long)batch * EMBED_DIM;      // 1.05M floats

    // ---- workspace layout ----
    char* wp = (char*)d_ws;
    float* bufA = (float*)wp;            wp += node_elems * sizeof(float);
    float* bufB = (float*)wp;            wp += node_elems * sizeof(float);
    float* uacc = (float*)wp;            wp += bacc_elems * sizeof(float);
    float* iacc = (float*)wp;            wp += bacc_elems * sizeof(float);
    int*   counts  = (int*)wp;           wp += (size_t)n_nodes * sizeof(int);
    int*   row_ptr = (int*)wp;           wp += (size_t)(n_nodes + 1) * sizeof(int);
    int*   bsum    = (int*)wp;           wp += 512 * sizeof(int);
    int*   boff    = (int*)wp;           wp += 512 * sizeof(int);
    wp = (char*)(((uintptr_t)wp + 15) & ~(uintptr_t)15);
    int2*  perm    = (int2*)wp;          wp += (size_t)nnz * sizeof(int2);
    // rank overlays bufB: bufB is first written as layer-2 output, long after
    // permute (the only consumer of rank) has completed on this stream.
    int*   rank    = (int*)bufB;

    const int nscan_blocks = (n_nodes + SCAN_CHUNK - 1) / SCAN_CHUNK;  // 293

    // ---- CSR build ----
    hipMemsetAsync(counts, 0, (size_t)n_nodes * sizeof(int), stream);
    hist_rank_kernel<<<2048, 256, 0, stream>>>(adj_rows, counts, rank, nnz);
    scan_phase1<<<nscan_blocks, 256, 0, stream>>>(counts, bsum, n_nodes);
    scan_phase2<<<1, 512, 0, stream>>>(bsum, boff, nscan_blocks);
    scan_phase3<<<nscan_blocks, 256, 0, stream>>>(counts, boff, row_ptr, n_nodes, nnz);
    permute_kernel<<<2048, 256, 0, stream>>>(adj_rows, adj_cols, adj_vals,
                                             row_ptr, rank, perm, nnz);

    // ---- batch accumulator init (layer-0 term) ----
    {
        int blocks = (batch * 16 + 255) / 256;
        init_bacc_kernel<<<blocks, 256, 0, stream>>>(user_emb, item_emb, user_ids, item_ids,
                                                     uacc, iacc, batch);
    }

    const int spmm_blocks = ((n_nodes * 64) + 255) / 256;   // one wave per row
    const int bblocks = (batch * 16 + 255) / 256;

    // ---- layer 1: concat(user_emb, item_emb) -> bufA ----
    spmm_csr_kernel<<<spmm_blocks, 256, 0, stream>>>(
        row_ptr, perm,
        user_emb, item_emb - (long)num_users * EMBED_DIM, num_users,
        bufA, n_nodes);
    bacc_add_kernel<<<bblocks, 256, 0, stream>>>(bufA, user_ids, item_ids,
                                                 uacc, iacc, batch, num_users);

    // ---- layer 2: bufA -> bufB ----
    spmm_csr_kernel<<<spmm_blocks, 256, 0, stream>>>(
        row_ptr, perm, bufA, bufA, 0x7fffffff, bufB, n_nodes);
    bacc_add_kernel<<<bblocks, 256, 0, stream>>>(bufB, user_ids, item_ids,
                                                 uacc, iacc, batch, num_users);

    // ---- layer 3: bufB -> bufA ----
    spmm_csr_kernel<<<spmm_blocks, 256, 0, stream>>>(
        row_ptr, perm, bufB, bufB, 0x7fffffff, bufA, n_nodes);
    bacc_add_kernel<<<bblocks, 256, 0, stream>>>(bufA, user_ids, item_ids,
                                                 uacc, iacc, batch, num_users);

    // ---- score ----
    {
        int blocks = (batch * 64 + 255) / 256;
        score_kernel<<<blocks, 256, 0, stream>>>(uacc, iacc, out, batch);
    }
}

// Round 5
// 1156.536 us; speedup vs baseline: 3.2603x; 1.0174x over previous
//
#include <hip/hip_runtime.h>

#define EMBED_DIM 64
#define NBLK_A 512            // blocks in bucket count/scatter passes
#define BUCKET_SHIFT 9        // 512 rows per bucket
#define BUCKET_ROWS 512
#define MAX_NBUCK 640
#define SCAN2_CHUNK 2048      // 256 threads x 8

typedef float fx4 __attribute__((ext_vector_type(4)));

// ---------- pass A1: per-block bucket histogram (LDS), bucket-major dump ----------
__global__ __launch_bounds__(256) void bucket_count_kernel(
    const int* __restrict__ rows, int* __restrict__ blockCounts,
    int nnz, int nbuck, int chunk) {
    __shared__ int hist[MAX_NBUCK];
    int t = threadIdx.x, blk = blockIdx.x;
    for (int i = t; i < nbuck; i += 256) hist[i] = 0;
    __syncthreads();
    int e0 = blk * chunk;
    int e1 = min(e0 + chunk, nnz);
    for (int e = e0 + t; e < e1; e += 256)
        atomicAdd(&hist[rows[e] >> BUCKET_SHIFT], 1);
    __syncthreads();
    for (int u = t; u < nbuck; u += 256)
        blockCounts[u * NBLK_A + blk] = hist[u];
}

// ---------- scan phase 1 (chunk 2048): per-block sums ----------
__global__ void scan8_phase1(const int* __restrict__ in, int* __restrict__ bsum, int n) {
    __shared__ int wsum[4];
    int t = threadIdx.x, b = blockIdx.x;
    int i0 = b * SCAN2_CHUNK + t * 8;
    int s = 0;
    #pragma unroll
    for (int k = 0; k < 8; ++k) { int i = i0 + k; if (i < n) s += in[i]; }
    #pragma unroll
    for (int off = 1; off < 64; off <<= 1) s += __shfl_xor(s, off);
    if ((t & 63) == 0) wsum[t >> 6] = s;
    __syncthreads();
    if (t == 0) bsum[b] = wsum[0] + wsum[1] + wsum[2] + wsum[3];
}

// ---------- scan phase 2: single-block scan of block sums (nb <= 512) ----------
__global__ void scan_phase2(const int* __restrict__ bsum, int* __restrict__ boff, int nb) {
    __shared__ int lds[512];
    int t = threadIdx.x;
    lds[t] = (t < nb) ? bsum[t] : 0;
    __syncthreads();
    for (int off = 1; off < 512; off <<= 1) {
        int v = (t >= off) ? lds[t - off] : 0;
        __syncthreads();
        lds[t] += v;
        __syncthreads();
    }
    if (t < nb) boff[t] = (t == 0) ? 0 : lds[t - 1];
}

// ---------- scan phase 3 (chunk 2048): write exclusive prefix ----------
__global__ void scan8_phase3(const int* __restrict__ in, const int* __restrict__ boff,
                             int* __restrict__ out, int n) {
    __shared__ int wexcl[4];
    int t = threadIdx.x, b = blockIdx.x;
    int lane = t & 63, w = t >> 6;
    int i0 = b * SCAN2_CHUNK + t * 8;
    int c[8];
    int s = 0;
    #pragma unroll
    for (int k = 0; k < 8; ++k) { int i = i0 + k; c[k] = (i < n) ? in[i] : 0; s += c[k]; }
    int incl = s;
    #pragma unroll
    for (int off = 1; off < 64; off <<= 1) {
        int u = __shfl_up(incl, off);
        if (lane >= off) incl += u;
    }
    if (lane == 63) wexcl[w] = incl;
    __syncthreads();
    int wbase = 0;
    for (int ww = 0; ww < w; ++ww) wbase += wexcl[ww];
    int run = incl - s + wbase + boff[b];
    #pragma unroll
    for (int k = 0; k < 8; ++k) {
        int i = i0 + k;
        if (i < n) { out[i] = run; run += c[k]; }
    }
}

// ---------- pass A3: scatter edges into bucket-partitioned staging (LDS cursors) ----------
__global__ __launch_bounds__(256) void bucket_scatter_kernel(
    const int* __restrict__ rows, const int* __restrict__ cols,
    const float* __restrict__ vals, const int* __restrict__ scanOut,
    int* __restrict__ srow, int2* __restrict__ scolval,
    int nnz, int nbuck, int chunk) {
    __shared__ int cur[MAX_NBUCK];
    int t = threadIdx.x, blk = blockIdx.x;
    for (int u = t; u < nbuck; u += 256) cur[u] = scanOut[u * NBLK_A + blk];
    __syncthreads();
    int e0 = blk * chunk;
    int e1 = min(e0 + chunk, nnz);
    for (int e = e0 + t; e < e1; e += 256) {
        int r = rows[e];
        int p = atomicAdd(&cur[r >> BUCKET_SHIFT], 1);
        srow[p] = r;
        scolval[p] = make_int2(cols[e], __float_as_int(vals[e]));
    }
}

// ---------- pass B: per-bucket counting sort -> row_ptr + perm ----------
__global__ __launch_bounds__(256) void bucket_build_kernel(
    const int* __restrict__ srow, const int2* __restrict__ scolval,
    const int* __restrict__ scanOut, int2* __restrict__ perm,
    int* __restrict__ row_ptr, int nnz, int n_nodes, int nbuck) {
    __shared__ int hist[BUCKET_ROWS], excl[BUCKET_ROWS], cur[BUCKET_ROWS];
    __shared__ int wex[4];
    int t = threadIdx.x, b = blockIdx.x;
    int lane = t & 63, w = t >> 6;
    int ebeg = scanOut[b * NBLK_A];
    int eend = (b + 1 < nbuck) ? scanOut[(b + 1) * NBLK_A] : nnz;
    hist[t] = 0; hist[t + 256] = 0;
    __syncthreads();
    for (int e = ebeg + t; e < eend; e += 256)
        atomicAdd(&hist[srow[e] & (BUCKET_ROWS - 1)], 1);
    __syncthreads();
    // 512-bin exclusive scan with 256 threads (2 bins each)
    int a = hist[2 * t], bcnt = hist[2 * t + 1];
    int s = a + bcnt;
    int incl = s;
    #pragma unroll
    for (int off = 1; off < 64; off <<= 1) {
        int u = __shfl_up(incl, off);
        if (lane >= off) incl += u;
    }
    if (lane == 63) wex[w] = incl;
    __syncthreads();
    int wbase = 0;
    for (int ww = 0; ww < w; ++ww) wbase += wex[ww];
    int es = wbase + incl - s;
    excl[2 * t] = es;
    excl[2 * t + 1] = es + a;
    cur[2 * t] = es;
    cur[2 * t + 1] = es + a;
    __syncthreads();
    // write row_ptr for this bucket's rows
    int base_row = b << BUCKET_SHIFT;
    for (int r = t; r < BUCKET_ROWS; r += 256) {
        int gr = base_row + r;
        if (gr < n_nodes) row_ptr[gr] = ebeg + excl[r];
    }
    if (b == 0 && t == 0) row_ptr[n_nodes] = nnz;
    // scatter (col,val) into final CSR order
    for (int e = ebeg + t; e < eend; e += 256) {
        int l = srow[e] & (BUCKET_ROWS - 1);
        int p = atomicAdd(&cur[l], 1);
        perm[ebeg + p] = scolval[e];
    }
}

// ---------- batch accumulator init (float4) ----------
__global__ void init_bacc_kernel(const float* __restrict__ ue, const float* __restrict__ ie,
                                 const int* __restrict__ uids, const int* __restrict__ iids,
                                 float* __restrict__ uacc, float* __restrict__ iacc, int batch) {
    int t = blockIdx.x * blockDim.x + threadIdx.x;
    if (t >= batch * 16) return;
    int b = t >> 4;
    int q = t & 15;
    const float4* ue4 = (const float4*)ue;
    const float4* ie4 = (const float4*)ie;
    ((float4*)uacc)[t] = ue4[(long)uids[b] * 16 + q];
    ((float4*)iacc)[t] = ie4[(long)iids[b] * 16 + q];
}

// ---------- CSR gather SpMM: one wave per row, 4 edges x float4 per iteration ----------
// perm reads and y stores are nontemporal to keep x resident in L2.
__global__ __launch_bounds__(256) void spmm_csr_kernel(
    const int* __restrict__ row_ptr, const int2* __restrict__ perm,
    const float* __restrict__ xu, const float* __restrict__ xi_off, int nu,
    float* __restrict__ y, int n_nodes) {
    int lane = threadIdx.x & 63;
    int row = (blockIdx.x * blockDim.x + threadIdx.x) >> 6;
    if (row >= n_nodes) return;
    int start = row_ptr[row];
    int end   = row_ptr[row + 1];
    int sub  = lane >> 4;    // edge slot 0..3
    int dimq = lane & 15;    // float4 index within the 64-dim row
    fx4 acc = (fx4)(0.f);
    for (int base = start; base < end; base += 4) {
        int e = base + sub;
        long long pv = 0;
        if (e < end) pv = __builtin_nontemporal_load((const long long*)&perm[e]);
        int   c = (int)pv;
        float v = __int_as_float((int)(pv >> 32));
        const float* xrow = (c < nu) ? (xu + (long)c * EMBED_DIM)
                                     : (xi_off + (long)c * EMBED_DIM);
        fx4 xv = reinterpret_cast<const fx4*>(xrow)[dimq];
        acc.x = fmaf(v, xv.x, acc.x);
        acc.y = fmaf(v, xv.y, acc.y);
        acc.z = fmaf(v, xv.z, acc.z);
        acc.w = fmaf(v, xv.w, acc.w);
    }
    // reduce across the 4 edge slots (xor lane bits 4,5)
    #pragma unroll
    for (int off = 16; off < 64; off <<= 1) {
        acc.x += __shfl_xor(acc.x, off);
        acc.y += __shfl_xor(acc.y, off);
        acc.z += __shfl_xor(acc.z, off);
        acc.w += __shfl_xor(acc.w, off);
    }
    if (sub == 0) {
        __builtin_nontemporal_store(acc, reinterpret_cast<fx4*>(y + (long)row * EMBED_DIM) + dimq);
    }
}

// ---------- per-layer batch accumulate (float4) ----------
__global__ void bacc_add_kernel(const float* __restrict__ y,
                                const int* __restrict__ uids, const int* __restrict__ iids,
                                float* __restrict__ uacc, float* __restrict__ iacc,
                                int batch, int num_users) {
    int t = blockIdx.x * blockDim.x + threadIdx.x;
    if (t >= batch * 16) return;
    int b = t >> 4;
    int q = t & 15;
    const float4* y4 = (const float4*)y;
    float4 u = y4[(long)uids[b] * 16 + q];
    float4 v = y4[((long)num_users + iids[b]) * 16 + q];
    float4* ua = (float4*)uacc;
    float4* ia = (float4*)iacc;
    float4 a = ua[t];
    a.x += u.x; a.y += u.y; a.z += u.z; a.w += u.w;
    ua[t] = a;
    float4 c = ia[t];
    c.x += v.x; c.y += v.y; c.z += v.z; c.w += v.w;
    ia[t] = c;
}

// ---------- scoring ----------
__global__ void score_kernel(const float* __restrict__ uacc, const float* __restrict__ iacc,
                             float* __restrict__ out, int batch) {
    int lane = threadIdx.x & 63;
    int w = (blockIdx.x * blockDim.x + threadIdx.x) >> 6;
    if (w >= batch) return;
    float p = uacc[(long)w * EMBED_DIM + lane] * iacc[(long)w * EMBED_DIM + lane];
    #pragma unroll
    for (int off = 32; off > 0; off >>= 1) p += __shfl_down(p, off);
    if (lane == 0) out[w] = p * (1.0f / 16.0f);  // (acc/4)·(acc/4)
}

extern "C" void kernel_launch(void* const* d_in, const int* in_sizes, int n_in,
                              void* d_out, int out_size, void* d_ws, size_t ws_size,
                              hipStream_t stream) {
    const float* user_emb = (const float*)d_in[0];
    const float* item_emb = (const float*)d_in[1];
    const int*   adj_rows = (const int*)d_in[2];
    const int*   adj_cols = (const int*)d_in[3];
    const float* adj_vals = (const float*)d_in[4];
    const int*   user_ids = (const int*)d_in[5];
    const int*   item_ids = (const int*)d_in[6];
    float* out = (float*)d_out;

    const int num_users = in_sizes[0] / EMBED_DIM;   // 200000
    const int num_items = in_sizes[1] / EMBED_DIM;   // 100000
    const int n_nodes   = num_users + num_items;     // 300000
    const int nnz       = in_sizes[2];               // 6000000
    const int batch     = in_sizes[5];               // 16384

    const long node_elems = (long)n_nodes * EMBED_DIM;    // 19.2M floats
    const long bacc_elems = (long)batch * EMBED_DIM;      // 1.05M floats

    const int nbuck = (n_nodes + BUCKET_ROWS - 1) >> BUCKET_SHIFT;   // 586
    const int nscan = nbuck * NBLK_A;                                // 300032
    const int nscan_blocks = (nscan + SCAN2_CHUNK - 1) / SCAN2_CHUNK; // 147

    // ---- workspace layout ----
    char* wp = (char*)d_ws;
    float* bufA = (float*)wp;            wp += node_elems * sizeof(float);
    float* bufB = (float*)wp;            wp += node_elems * sizeof(float);
    float* uacc = (float*)wp;            wp += bacc_elems * sizeof(float);
    float* iacc = (float*)wp;            wp += bacc_elems * sizeof(float);
    int*   row_ptr = (int*)wp;           wp += (size_t)(n_nodes + 1) * sizeof(int);
    int*   bsum    = (int*)wp;           wp += 512 * sizeof(int);
    int*   boff    = (int*)wp;           wp += 512 * sizeof(int);
    wp = (char*)(((uintptr_t)wp + 15) & ~(uintptr_t)15);
    int2*  perm    = (int2*)wp;          wp += (size_t)nnz * sizeof(int2);

    // overlays (dead before their regions are first written by the layer loop):
    // staging srow/scolval live in bufA until bucket_build completes (bufA first
    // written by layer-1 spmm, which runs after). blockCounts/scanOut live in bufB
    // (first written by layer-2 spmm).
    int*  srow    = (int*)bufA;                                  // nnz ints (24 MB)
    int2* scolval = (int2*)((char*)bufA + (size_t)nnz * sizeof(int)); // nnz int2 (48 MB)
    int*  blockCounts = (int*)bufB;                              // nscan ints
    int*  scanOut     = blockCounts + nscan;                     // nscan ints

    const int chunkA = (nnz + NBLK_A - 1) / NBLK_A;              // 11719

    // ---- radix CSR build (no device atomics) ----
    bucket_count_kernel<<<NBLK_A, 256, 0, stream>>>(adj_rows, blockCounts, nnz, nbuck, chunkA);
    scan8_phase1<<<nscan_blocks, 256, 0, stream>>>(blockCounts, bsum, nscan);
    scan_phase2<<<1, 512, 0, stream>>>(bsum, boff, nscan_blocks);
    scan8_phase3<<<nscan_blocks, 256, 0, stream>>>(blockCounts, boff, scanOut, nscan);
    bucket_scatter_kernel<<<NBLK_A, 256, 0, stream>>>(adj_rows, adj_cols, adj_vals,
                                                      scanOut, srow, scolval,
                                                      nnz, nbuck, chunkA);
    bucket_build_kernel<<<nbuck, 256, 0, stream>>>(srow, scolval, scanOut, perm,
                                                   row_ptr, nnz, n_nodes, nbuck);

    // ---- batch accumulator init (layer-0 term) ----
    {
        int blocks = (batch * 16 + 255) / 256;
        init_bacc_kernel<<<blocks, 256, 0, stream>>>(user_emb, item_emb, user_ids, item_ids,
                                                     uacc, iacc, batch);
    }

    const int spmm_blocks = ((n_nodes * 64) + 255) / 256;   // one wave per row
    const int bblocks = (batch * 16 + 255) / 256;

    // ---- layer 1: concat(user_emb, item_emb) -> bufA ----
    spmm_csr_kernel<<<spmm_blocks, 256, 0, stream>>>(
        row_ptr, perm,
        user_emb, item_emb - (long)num_users * EMBED_DIM, num_users,
        bufA, n_nodes);
    bacc_add_kernel<<<bblocks, 256, 0, stream>>>(bufA, user_ids, item_ids,
                                                 uacc, iacc, batch, num_users);

    // ---- layer 2: bufA -> bufB ----
    spmm_csr_kernel<<<spmm_blocks, 256, 0, stream>>>(
        row_ptr, perm, bufA, bufA, 0x7fffffff, bufB, n_nodes);
    bacc_add_kernel<<<bblocks, 256, 0, stream>>>(bufB, user_ids, item_ids,
                                                 uacc, iacc, batch, num_users);

    // ---- layer 3: bufB -> bufA ----
    spmm_csr_kernel<<<spmm_blocks, 256, 0, stream>>>(
        row_ptr, perm, bufB, bufB, 0x7fffffff, bufA, n_nodes);
    bacc_add_kernel<<<bblocks, 256, 0, stream>>>(bufA, user_ids, item_ids,
                                                 uacc, iacc, batch, num_users);

    // ---- score ----
    {
        int blocks = (batch * 64 + 255) / 256;
        score_kernel<<<blocks, 256, 0, stream>>>(uacc, iacc, out, batch);
    }
}

// Round 6
// 999.948 us; speedup vs baseline: 3.7708x; 1.1566x over previous
//
#include <hip/hip_runtime.h>

#define EMBED_DIM 64
#define NBLK_A 512            // blocks in bucket count/scatter passes
#define BUCKET_SHIFT 9        // 512 rows per bucket
#define BUCKET_ROWS 512
#define MAX_NBUCK 640
#define SCAN2_CHUNK 2048      // 256 threads x 8

typedef float fx4 __attribute__((ext_vector_type(4)));

// ---------- pass A1: per-block bucket histogram (LDS), bucket-major dump ----------
// chunk is a multiple of 1024 (so int4 loads are aligned and tail-free; nnz % 4 == 0).
__global__ __launch_bounds__(256) void bucket_count_kernel(
    const int* __restrict__ rows, int* __restrict__ blockCounts,
    int nnz, int nbuck, int chunk) {
    __shared__ int hist[MAX_NBUCK];
    int t = threadIdx.x, blk = blockIdx.x;
    for (int i = t; i < nbuck; i += 256) hist[i] = 0;
    __syncthreads();
    int e0 = blk * chunk;
    int e1 = min(e0 + chunk, nnz);
    for (int e = e0 + t * 4; e < e1; e += 1024) {
        int4 r4 = *reinterpret_cast<const int4*>(rows + e);
        atomicAdd(&hist[r4.x >> BUCKET_SHIFT], 1);
        atomicAdd(&hist[r4.y >> BUCKET_SHIFT], 1);
        atomicAdd(&hist[r4.z >> BUCKET_SHIFT], 1);
        atomicAdd(&hist[r4.w >> BUCKET_SHIFT], 1);
    }
    __syncthreads();
    for (int u = t; u < nbuck; u += 256)
        blockCounts[u * NBLK_A + blk] = hist[u];
}

// ---------- scan phase 1 (chunk 2048): per-block sums ----------
__global__ void scan8_phase1(const int* __restrict__ in, int* __restrict__ bsum, int n) {
    __shared__ int wsum[4];
    int t = threadIdx.x, b = blockIdx.x;
    int i0 = b * SCAN2_CHUNK + t * 8;
    int s = 0;
    #pragma unroll
    for (int k = 0; k < 8; ++k) { int i = i0 + k; if (i < n) s += in[i]; }
    #pragma unroll
    for (int off = 1; off < 64; off <<= 1) s += __shfl_xor(s, off);
    if ((t & 63) == 0) wsum[t >> 6] = s;
    __syncthreads();
    if (t == 0) bsum[b] = wsum[0] + wsum[1] + wsum[2] + wsum[3];
}

// ---------- scan phase 2: single-block scan of block sums (nb <= 512) ----------
__global__ void scan_phase2(const int* __restrict__ bsum, int* __restrict__ boff, int nb) {
    __shared__ int lds[512];
    int t = threadIdx.x;
    lds[t] = (t < nb) ? bsum[t] : 0;
    __syncthreads();
    for (int off = 1; off < 512; off <<= 1) {
        int v = (t >= off) ? lds[t - off] : 0;
        __syncthreads();
        lds[t] += v;
        __syncthreads();
    }
    if (t < nb) boff[t] = (t == 0) ? 0 : lds[t - 1];
}

// ---------- scan phase 3 (chunk 2048): write exclusive prefix ----------
__global__ void scan8_phase3(const int* __restrict__ in, const int* __restrict__ boff,
                             int* __restrict__ out, int n) {
    __shared__ int wexcl[4];
    int t = threadIdx.x, b = blockIdx.x;
    int lane = t & 63, w = t >> 6;
    int i0 = b * SCAN2_CHUNK + t * 8;
    int c[8];
    int s = 0;
    #pragma unroll
    for (int k = 0; k < 8; ++k) { int i = i0 + k; c[k] = (i < n) ? in[i] : 0; s += c[k]; }
    int incl = s;
    #pragma unroll
    for (int off = 1; off < 64; off <<= 1) {
        int u = __shfl_up(incl, off);
        if (lane >= off) incl += u;
    }
    if (lane == 63) wexcl[w] = incl;
    __syncthreads();
    int wbase = 0;
    for (int ww = 0; ww < w; ++ww) wbase += wexcl[ww];
    int run = incl - s + wbase + boff[b];
    #pragma unroll
    for (int k = 0; k < 8; ++k) {
        int i = i0 + k;
        if (i < n) { out[i] = run; run += c[k]; }
    }
}

// ---------- pass A3: scatter edges into bucket-partitioned staging (LDS cursors) ----------
__global__ __launch_bounds__(256) void bucket_scatter_kernel(
    const int* __restrict__ rows, const int* __restrict__ cols,
    const float* __restrict__ vals, const int* __restrict__ scanOut,
    int* __restrict__ srow, int2* __restrict__ scolval,
    int nnz, int nbuck, int chunk) {
    __shared__ int cur[MAX_NBUCK];
    int t = threadIdx.x, blk = blockIdx.x;
    for (int u = t; u < nbuck; u += 256) cur[u] = scanOut[u * NBLK_A + blk];
    __syncthreads();
    int e0 = blk * chunk;
    int e1 = min(e0 + chunk, nnz);
    for (int e = e0 + t * 4; e < e1; e += 1024) {
        int4   r4 = *reinterpret_cast<const int4*>(rows + e);
        int4   c4 = *reinterpret_cast<const int4*>(cols + e);
        float4 v4 = *reinterpret_cast<const float4*>(vals + e);
        int p0 = atomicAdd(&cur[r4.x >> BUCKET_SHIFT], 1);
        srow[p0] = r4.x; scolval[p0] = make_int2(c4.x, __float_as_int(v4.x));
        int p1 = atomicAdd(&cur[r4.y >> BUCKET_SHIFT], 1);
        srow[p1] = r4.y; scolval[p1] = make_int2(c4.y, __float_as_int(v4.y));
        int p2 = atomicAdd(&cur[r4.z >> BUCKET_SHIFT], 1);
        srow[p2] = r4.z; scolval[p2] = make_int2(c4.z, __float_as_int(v4.z));
        int p3 = atomicAdd(&cur[r4.w >> BUCKET_SHIFT], 1);
        srow[p3] = r4.w; scolval[p3] = make_int2(c4.w, __float_as_int(v4.w));
    }
}

// ---------- pass B: per-bucket counting sort -> row_ptr + perm ----------
__global__ __launch_bounds__(256) void bucket_build_kernel(
    const int* __restrict__ srow, const int2* __restrict__ scolval,
    const int* __restrict__ scanOut, int2* __restrict__ perm,
    int* __restrict__ row_ptr, int nnz, int n_nodes, int nbuck) {
    __shared__ int hist[BUCKET_ROWS], excl[BUCKET_ROWS], cur[BUCKET_ROWS];
    __shared__ int wex[4];
    int t = threadIdx.x, b = blockIdx.x;
    int lane = t & 63, w = t >> 6;
    int ebeg = scanOut[b * NBLK_A];
    int eend = (b + 1 < nbuck) ? scanOut[(b + 1) * NBLK_A] : nnz;
    hist[t] = 0; hist[t + 256] = 0;
    __syncthreads();
    for (int e = ebeg + t; e < eend; e += 256)
        atomicAdd(&hist[srow[e] & (BUCKET_ROWS - 1)], 1);
    __syncthreads();
    // 512-bin exclusive scan with 256 threads (2 bins each)
    int a = hist[2 * t], bcnt = hist[2 * t + 1];
    int s = a + bcnt;
    int incl = s;
    #pragma unroll
    for (int off = 1; off < 64; off <<= 1) {
        int u = __shfl_up(incl, off);
        if (lane >= off) incl += u;
    }
    if (lane == 63) wex[w] = incl;
    __syncthreads();
    int wbase = 0;
    for (int ww = 0; ww < w; ++ww) wbase += wex[ww];
    int es = wbase + incl - s;
    excl[2 * t] = es;
    excl[2 * t + 1] = es + a;
    cur[2 * t] = es;
    cur[2 * t + 1] = es + a;
    __syncthreads();
    // write row_ptr for this bucket's rows
    int base_row = b << BUCKET_SHIFT;
    for (int r = t; r < BUCKET_ROWS; r += 256) {
        int gr = base_row + r;
        if (gr < n_nodes) row_ptr[gr] = ebeg + excl[r];
    }
    if (b == 0 && t == 0) row_ptr[n_nodes] = nnz;
    // scatter (col,val) into final CSR order
    for (int e = ebeg + t; e < eend; e += 256) {
        int l = srow[e] & (BUCKET_ROWS - 1);
        int p = atomicAdd(&cur[l], 1);
        perm[ebeg + p] = scolval[e];
    }
}

// ---------- batch accumulator init (float4) ----------
__global__ void init_bacc_kernel(const float* __restrict__ ue, const float* __restrict__ ie,
                                 const int* __restrict__ uids, const int* __restrict__ iids,
                                 float* __restrict__ uacc, float* __restrict__ iacc, int batch) {
    int t = blockIdx.x * blockDim.x + threadIdx.x;
    if (t >= batch * 16) return;
    int b = t >> 4;
    int q = t & 15;
    const float4* ue4 = (const float4*)ue;
    const float4* ie4 = (const float4*)ie;
    ((float4*)uacc)[t] = ue4[(long)uids[b] * 16 + q];
    ((float4*)iacc)[t] = ie4[(long)iids[b] * 16 + q];
}

// ---------- CSR gather SpMM: one wave per row, 4 edges x float4 per iteration ----------
__global__ __launch_bounds__(256) void spmm_csr_kernel(
    const int* __restrict__ row_ptr, const int2* __restrict__ perm,
    const float* __restrict__ xu, const float* __restrict__ xi_off, int nu,
    float* __restrict__ y, int n_nodes) {
    int lane = threadIdx.x & 63;
    int row = (blockIdx.x * blockDim.x + threadIdx.x) >> 6;
    if (row >= n_nodes) return;
    int start = row_ptr[row];
    int end   = row_ptr[row + 1];
    int sub  = lane >> 4;    // edge slot 0..3
    int dimq = lane & 15;    // float4 index within the 64-dim row
    fx4 acc = (fx4)(0.f);
    for (int base = start; base < end; base += 4) {
        int e = base + sub;
        int2 p = make_int2(0, 0);               // val=0 -> contributes nothing
        if (e < end) p = perm[e];
        int   c = p.x;
        float v = __int_as_float(p.y);
        const float* xrow = (c < nu) ? (xu + (long)c * EMBED_DIM)
                                     : (xi_off + (long)c * EMBED_DIM);
        fx4 xv = reinterpret_cast<const fx4*>(xrow)[dimq];
        acc.x = fmaf(v, xv.x, acc.x);
        acc.y = fmaf(v, xv.y, acc.y);
        acc.z = fmaf(v, xv.z, acc.z);
        acc.w = fmaf(v, xv.w, acc.w);
    }
    // reduce across the 4 edge slots (xor lane bits 4,5)
    #pragma unroll
    for (int off = 16; off < 64; off <<= 1) {
        acc.x += __shfl_xor(acc.x, off);
        acc.y += __shfl_xor(acc.y, off);
        acc.z += __shfl_xor(acc.z, off);
        acc.w += __shfl_xor(acc.w, off);
    }
    if (sub == 0) {
        reinterpret_cast<fx4*>(y + (long)row * EMBED_DIM)[dimq] = acc;
    }
}

// ---------- per-layer batch accumulate (float4) ----------
__global__ void bacc_add_kernel(const float* __restrict__ y,
                                const int* __restrict__ uids, const int* __restrict__ iids,
                                float* __restrict__ uacc, float* __restrict__ iacc,
                                int batch, int num_users) {
    int t = blockIdx.x * blockDim.x + threadIdx.x;
    if (t >= batch * 16) return;
    int b = t >> 4;
    int q = t & 15;
    const float4* y4 = (const float4*)y;
    float4 u = y4[(long)uids[b] * 16 + q];
    float4 v = y4[((long)num_users + iids[b]) * 16 + q];
    float4* ua = (float4*)uacc;
    float4* ia = (float4*)iacc;
    float4 a = ua[t];
    a.x += u.x; a.y += u.y; a.z += u.z; a.w += u.w;
    ua[t] = a;
    float4 c = ia[t];
    c.x += v.x; c.y += v.y; c.z += v.z; c.w += v.w;
    ia[t] = c;
}

// ---------- scoring ----------
__global__ void score_kernel(const float* __restrict__ uacc, const float* __restrict__ iacc,
                             float* __restrict__ out, int batch) {
    int lane = threadIdx.x & 63;
    int w = (blockIdx.x * blockDim.x + threadIdx.x) >> 6;
    if (w >= batch) return;
    float p = uacc[(long)w * EMBED_DIM + lane] * iacc[(long)w * EMBED_DIM + lane];
    #pragma unroll
    for (int off = 32; off > 0; off >>= 1) p += __shfl_down(p, off);
    if (lane == 0) out[w] = p * (1.0f / 16.0f);  // (acc/4)·(acc/4)
}

extern "C" void kernel_launch(void* const* d_in, const int* in_sizes, int n_in,
                              void* d_out, int out_size, void* d_ws, size_t ws_size,
                              hipStream_t stream) {
    const float* user_emb = (const float*)d_in[0];
    const float* item_emb = (const float*)d_in[1];
    const int*   adj_rows = (const int*)d_in[2];
    const int*   adj_cols = (const int*)d_in[3];
    const float* adj_vals = (const float*)d_in[4];
    const int*   user_ids = (const int*)d_in[5];
    const int*   item_ids = (const int*)d_in[6];
    float* out = (float*)d_out;

    const int num_users = in_sizes[0] / EMBED_DIM;   // 200000
    const int num_items = in_sizes[1] / EMBED_DIM;   // 100000
    const int n_nodes   = num_users + num_items;     // 300000
    const int nnz       = in_sizes[2];               // 6000000
    const int batch     = in_sizes[5];               // 16384

    const long node_elems = (long)n_nodes * EMBED_DIM;    // 19.2M floats
    const long bacc_elems = (long)batch * EMBED_DIM;      // 1.05M floats

    const int nbuck = (n_nodes + BUCKET_ROWS - 1) >> BUCKET_SHIFT;   // 586
    const int nscan = nbuck * NBLK_A;                                // 300032
    const int nscan_blocks = (nscan + SCAN2_CHUNK - 1) / SCAN2_CHUNK; // 147

    // ---- workspace layout ----
    char* wp = (char*)d_ws;
    float* bufA = (float*)wp;            wp += node_elems * sizeof(float);
    float* bufB = (float*)wp;            wp += node_elems * sizeof(float);
    float* uacc = (float*)wp;            wp += bacc_elems * sizeof(float);
    float* iacc = (float*)wp;            wp += bacc_elems * sizeof(float);
    int*   row_ptr = (int*)wp;           wp += (size_t)(n_nodes + 1) * sizeof(int);
    int*   bsum    = (int*)wp;           wp += 512 * sizeof(int);
    int*   boff    = (int*)wp;           wp += 512 * sizeof(int);
    wp = (char*)(((uintptr_t)wp + 15) & ~(uintptr_t)15);
    int2*  perm    = (int2*)wp;          wp += (size_t)nnz * sizeof(int2);

    // overlays (dead before their regions are first written by the layer loop):
    // staging srow/scolval live in bufA until bucket_build completes (bufA first
    // written by layer-1 spmm, which runs after). blockCounts/scanOut live in bufB
    // (first written by layer-2 spmm).
    int*  srow    = (int*)bufA;                                  // nnz ints (24 MB)
    int2* scolval = (int2*)((char*)bufA + (size_t)nnz * sizeof(int)); // nnz int2 (48 MB)
    int*  blockCounts = (int*)bufB;                              // nscan ints
    int*  scanOut     = blockCounts + nscan;                     // nscan ints

    // chunk rounded to 1024 so every block's range is int4-aligned and tail-free
    const int chunkA = (((nnz + NBLK_A - 1) / NBLK_A) + 1023) & ~1023;   // 12288

    // ---- radix CSR build (no device atomics) ----
    bucket_count_kernel<<<NBLK_A, 256, 0, stream>>>(adj_rows, blockCounts, nnz, nbuck, chunkA);
    scan8_phase1<<<nscan_blocks, 256, 0, stream>>>(blockCounts, bsum, nscan);
    scan_phase2<<<1, 512, 0, stream>>>(bsum, boff, nscan_blocks);
    scan8_phase3<<<nscan_blocks, 256, 0, stream>>>(blockCounts, boff, scanOut, nscan);
    bucket_scatter_kernel<<<NBLK_A, 256, 0, stream>>>(adj_rows, adj_cols, adj_vals,
                                                      scanOut, srow, scolval,
                                                      nnz, nbuck, chunkA);
    bucket_build_kernel<<<nbuck, 256, 0, stream>>>(srow, scolval, scanOut, perm,
                                                   row_ptr, nnz, n_nodes, nbuck);

    // ---- batch accumulator init (layer-0 term) ----
    {
        int blocks = (batch * 16 + 255) / 256;
        init_bacc_kernel<<<blocks, 256, 0, stream>>>(user_emb, item_emb, user_ids, item_ids,
                                                     uacc, iacc, batch);
    }

    const int spmm_blocks = ((n_nodes * 64) + 255) / 256;   // one wave per row
    const int bblocks = (batch * 16 + 255) / 256;

    // ---- layer 1: concat(user_emb, item_emb) -> bufA ----
    spmm_csr_kernel<<<spmm_blocks, 256, 0, stream>>>(
        row_ptr, perm,
        user_emb, item_emb - (long)num_users * EMBED_DIM, num_users,
        bufA, n_nodes);
    bacc_add_kernel<<<bblocks, 256, 0, stream>>>(bufA, user_ids, item_ids,
                                                 uacc, iacc, batch, num_users);

    // ---- layer 2: bufA -> bufB ----
    spmm_csr_kernel<<<spmm_blocks, 256, 0, stream>>>(
        row_ptr, perm, bufA, bufA, 0x7fffffff, bufB, n_nodes);
    bacc_add_kernel<<<bblocks, 256, 0, stream>>>(bufB, user_ids, item_ids,
                                                 uacc, iacc, batch, num_users);

    // ---- layer 3: bufB -> bufA ----
    spmm_csr_kernel<<<spmm_blocks, 256, 0, stream>>>(
        row_ptr, perm, bufB, bufB, 0x7fffffff, bufA, n_nodes);
    bacc_add_kernel<<<bblocks, 256, 0, stream>>>(bufA, user_ids, item_ids,
                                                 uacc, iacc, batch, num_users);

    // ---- score ----
    {
        int blocks = (batch * 64 + 255) / 256;
        score_kernel<<<blocks, 256, 0, stream>>>(uacc, iacc, out, batch);
    }
}

// Round 7
// 880.315 us; speedup vs baseline: 4.2833x; 1.1359x over previous
//
#include <hip/hip_runtime.h>

#define EMBED_DIM 64
#define NBLK_A 256            // blocks in bucket count/scatter passes
#define BUCKET_SHIFT 9        // 512 rows per bucket
#define BUCKET_ROWS 512
#define MAX_NBUCK 640
#define SCAN2_CHUNK 2048      // 256 threads x 8
#define COL_BITS 19           // col < 2^19; meta = (localrow << 19) | col

typedef float fx4 __attribute__((ext_vector_type(4)));

// ---------- pass A1: per-block bucket histogram (LDS), bucket-major dump ----------
// chunk is a multiple of 1024 (int4 loads aligned, tail-free; nnz % 4 == 0).
__global__ __launch_bounds__(256) void bucket_count_kernel(
    const int* __restrict__ rows, int* __restrict__ blockCounts,
    int nnz, int nbuck, int chunk) {
    __shared__ int hist[MAX_NBUCK];
    int t = threadIdx.x, blk = blockIdx.x;
    for (int i = t; i < nbuck; i += 256) hist[i] = 0;
    __syncthreads();
    int e0 = blk * chunk;
    int e1 = min(e0 + chunk, nnz);
    for (int e = e0 + t * 4; e < e1; e += 1024) {
        int4 r4 = *reinterpret_cast<const int4*>(rows + e);
        atomicAdd(&hist[r4.x >> BUCKET_SHIFT], 1);
        atomicAdd(&hist[r4.y >> BUCKET_SHIFT], 1);
        atomicAdd(&hist[r4.z >> BUCKET_SHIFT], 1);
        atomicAdd(&hist[r4.w >> BUCKET_SHIFT], 1);
    }
    __syncthreads();
    for (int u = t; u < nbuck; u += 256)
        blockCounts[u * NBLK_A + blk] = hist[u];
}

// ---------- scan phase 1 (chunk 2048): per-block sums ----------
__global__ void scan8_phase1(const int* __restrict__ in, int* __restrict__ bsum, int n) {
    __shared__ int wsum[4];
    int t = threadIdx.x, b = blockIdx.x;
    int i0 = b * SCAN2_CHUNK + t * 8;
    int s = 0;
    #pragma unroll
    for (int k = 0; k < 8; ++k) { int i = i0 + k; if (i < n) s += in[i]; }
    #pragma unroll
    for (int off = 1; off < 64; off <<= 1) s += __shfl_xor(s, off);
    if ((t & 63) == 0) wsum[t >> 6] = s;
    __syncthreads();
    if (t == 0) bsum[b] = wsum[0] + wsum[1] + wsum[2] + wsum[3];
}

// ---------- scan phase 2: single-block scan of block sums (nb <= 512) ----------
__global__ void scan_phase2(const int* __restrict__ bsum, int* __restrict__ boff, int nb) {
    __shared__ int lds[512];
    int t = threadIdx.x;
    lds[t] = (t < nb) ? bsum[t] : 0;
    __syncthreads();
    for (int off = 1; off < 512; off <<= 1) {
        int v = (t >= off) ? lds[t - off] : 0;
        __syncthreads();
        lds[t] += v;
        __syncthreads();
    }
    if (t < nb) boff[t] = (t == 0) ? 0 : lds[t - 1];
}

// ---------- scan phase 3 (chunk 2048): write exclusive prefix ----------
__global__ void scan8_phase3(const int* __restrict__ in, const int* __restrict__ boff,
                             int* __restrict__ out, int n) {
    __shared__ int wexcl[4];
    int t = threadIdx.x, b = blockIdx.x;
    int lane = t & 63, w = t >> 6;
    int i0 = b * SCAN2_CHUNK + t * 8;
    int c[8];
    int s = 0;
    #pragma unroll
    for (int k = 0; k < 8; ++k) { int i = i0 + k; c[k] = (i < n) ? in[i] : 0; s += c[k]; }
    int incl = s;
    #pragma unroll
    for (int off = 1; off < 64; off <<= 1) {
        int u = __shfl_up(incl, off);
        if (lane >= off) incl += u;
    }
    if (lane == 63) wexcl[w] = incl;
    __syncthreads();
    int wbase = 0;
    for (int ww = 0; ww < w; ++ww) wbase += wexcl[ww];
    int run = incl - s + wbase + boff[b];
    #pragma unroll
    for (int k = 0; k < 8; ++k) {
        int i = i0 + k;
        if (i < n) { out[i] = run; run += c[k]; }
    }
}

// ---------- pass A3: scatter edges into bucket-partitioned staging (LDS cursors) ----------
// One 8-byte scattered write per edge: smeta = ((row & 511) << COL_BITS) | col, val.
__global__ __launch_bounds__(256) void bucket_scatter_kernel(
    const int* __restrict__ rows, const int* __restrict__ cols,
    const float* __restrict__ vals, const int* __restrict__ scanOut,
    int2* __restrict__ smeta, int nnz, int nbuck, int chunk) {
    __shared__ int cur[MAX_NBUCK];
    int t = threadIdx.x, blk = blockIdx.x;
    for (int u = t; u < nbuck; u += 256) cur[u] = scanOut[u * NBLK_A + blk];
    __syncthreads();
    int e0 = blk * chunk;
    int e1 = min(e0 + chunk, nnz);
    for (int e = e0 + t * 4; e < e1; e += 1024) {
        int4   r4 = *reinterpret_cast<const int4*>(rows + e);
        int4   c4 = *reinterpret_cast<const int4*>(cols + e);
        float4 v4 = *reinterpret_cast<const float4*>(vals + e);
        int p0 = atomicAdd(&cur[r4.x >> BUCKET_SHIFT], 1);
        smeta[p0] = make_int2(((r4.x & (BUCKET_ROWS - 1)) << COL_BITS) | c4.x, __float_as_int(v4.x));
        int p1 = atomicAdd(&cur[r4.y >> BUCKET_SHIFT], 1);
        smeta[p1] = make_int2(((r4.y & (BUCKET_ROWS - 1)) << COL_BITS) | c4.y, __float_as_int(v4.y));
        int p2 = atomicAdd(&cur[r4.z >> BUCKET_SHIFT], 1);
        smeta[p2] = make_int2(((r4.z & (BUCKET_ROWS - 1)) << COL_BITS) | c4.z, __float_as_int(v4.z));
        int p3 = atomicAdd(&cur[r4.w >> BUCKET_SHIFT], 1);
        smeta[p3] = make_int2(((r4.w & (BUCKET_ROWS - 1)) << COL_BITS) | c4.w, __float_as_int(v4.w));
    }
}

// ---------- pass B: per-bucket counting sort -> row_ptr + perm ----------
__global__ __launch_bounds__(256) void bucket_build_kernel(
    const int2* __restrict__ smeta, const int* __restrict__ scanOut,
    int2* __restrict__ perm, int* __restrict__ row_ptr,
    int nnz, int n_nodes, int nbuck) {
    __shared__ int hist[BUCKET_ROWS], excl[BUCKET_ROWS], cur[BUCKET_ROWS];
    __shared__ int wex[4];
    int t = threadIdx.x, b = blockIdx.x;
    int lane = t & 63, w = t >> 6;
    int ebeg = scanOut[b * NBLK_A];
    int eend = (b + 1 < nbuck) ? scanOut[(b + 1) * NBLK_A] : nnz;
    hist[t] = 0; hist[t + 256] = 0;
    __syncthreads();
    for (int e = ebeg + t; e < eend; e += 256)
        atomicAdd(&hist[smeta[e].x >> COL_BITS], 1);
    __syncthreads();
    // 512-bin exclusive scan with 256 threads (2 bins each)
    int a = hist[2 * t], bcnt = hist[2 * t + 1];
    int s = a + bcnt;
    int incl = s;
    #pragma unroll
    for (int off = 1; off < 64; off <<= 1) {
        int u = __shfl_up(incl, off);
        if (lane >= off) incl += u;
    }
    if (lane == 63) wex[w] = incl;
    __syncthreads();
    int wbase = 0;
    for (int ww = 0; ww < w; ++ww) wbase += wex[ww];
    int es = wbase + incl - s;
    excl[2 * t] = es;
    excl[2 * t + 1] = es + a;
    cur[2 * t] = es;
    cur[2 * t + 1] = es + a;
    __syncthreads();
    // write row_ptr for this bucket's rows
    int base_row = b << BUCKET_SHIFT;
    for (int r = t; r < BUCKET_ROWS; r += 256) {
        int gr = base_row + r;
        if (gr < n_nodes) row_ptr[gr] = ebeg + excl[r];
    }
    if (b == 0 && t == 0) row_ptr[n_nodes] = nnz;
    // scatter (col,val) into final CSR order
    for (int e = ebeg + t; e < eend; e += 256) {
        int2 m = smeta[e];
        int l = m.x >> COL_BITS;
        int p = atomicAdd(&cur[l], 1);
        perm[ebeg + p] = make_int2(m.x & ((1 << COL_BITS) - 1), m.y);
    }
}

// ---------- batch accumulator init (float4) ----------
__global__ void init_bacc_kernel(const float* __restrict__ ue, const float* __restrict__ ie,
                                 const int* __restrict__ uids, const int* __restrict__ iids,
                                 float* __restrict__ uacc, float* __restrict__ iacc, int batch) {
    int t = blockIdx.x * blockDim.x + threadIdx.x;
    if (t >= batch * 16) return;
    int b = t >> 4;
    int q = t & 15;
    const float4* ue4 = (const float4*)ue;
    const float4* ie4 = (const float4*)ie;
    ((float4*)uacc)[t] = ue4[(long)uids[b] * 16 + q];
    ((float4*)iacc)[t] = ie4[(long)iids[b] * 16 + q];
}

// ---------- CSR gather SpMM: one wave per row, 8 edges x float4 per iteration ----------
// Two independent 4-edge groups in flight per iteration (2x memory-level parallelism).
__global__ __launch_bounds__(256) void spmm_csr_kernel(
    const int* __restrict__ row_ptr, const int2* __restrict__ perm,
    const float* __restrict__ xu, const float* __restrict__ xi_off, int nu,
    float* __restrict__ y, int n_nodes) {
    int lane = threadIdx.x & 63;
    int row = (blockIdx.x * blockDim.x + threadIdx.x) >> 6;
    if (row >= n_nodes) return;
    int start = row_ptr[row];
    int end   = row_ptr[row + 1];
    int sub  = lane >> 4;    // edge slot 0..3
    int dimq = lane & 15;    // float4 index within the 64-dim row
    fx4 acc0 = (fx4)(0.f);
    fx4 acc1 = (fx4)(0.f);
    for (int base = start; base < end; base += 8) {
        int e0 = base + sub;
        int e1 = e0 + 4;
        int2 p0 = make_int2(0, 0);
        int2 p1 = make_int2(0, 0);
        if (e0 < end) p0 = perm[e0];
        if (e1 < end) p1 = perm[e1];
        float v0 = __int_as_float(p0.y);
        float v1 = __int_as_float(p1.y);
        const float* xr0 = (p0.x < nu) ? (xu + (long)p0.x * EMBED_DIM)
                                       : (xi_off + (long)p0.x * EMBED_DIM);
        const float* xr1 = (p1.x < nu) ? (xu + (long)p1.x * EMBED_DIM)
                                       : (xi_off + (long)p1.x * EMBED_DIM);
        fx4 xv0 = reinterpret_cast<const fx4*>(xr0)[dimq];
        fx4 xv1 = reinterpret_cast<const fx4*>(xr1)[dimq];
        acc0.x = fmaf(v0, xv0.x, acc0.x);
        acc0.y = fmaf(v0, xv0.y, acc0.y);
        acc0.z = fmaf(v0, xv0.z, acc0.z);
        acc0.w = fmaf(v0, xv0.w, acc0.w);
        acc1.x = fmaf(v1, xv1.x, acc1.x);
        acc1.y = fmaf(v1, xv1.y, acc1.y);
        acc1.z = fmaf(v1, xv1.z, acc1.z);
        acc1.w = fmaf(v1, xv1.w, acc1.w);
    }
    fx4 acc;
    acc.x = acc0.x + acc1.x;
    acc.y = acc0.y + acc1.y;
    acc.z = acc0.z + acc1.z;
    acc.w = acc0.w + acc1.w;
    // reduce across the 4 edge slots (xor lane bits 4,5)
    #pragma unroll
    for (int off = 16; off < 64; off <<= 1) {
        acc.x += __shfl_xor(acc.x, off);
        acc.y += __shfl_xor(acc.y, off);
        acc.z += __shfl_xor(acc.z, off);
        acc.w += __shfl_xor(acc.w, off);
    }
    if (sub == 0) {
        reinterpret_cast<fx4*>(y + (long)row * EMBED_DIM)[dimq] = acc;
    }
}

// ---------- per-layer batch accumulate (float4) ----------
__global__ void bacc_add_kernel(const float* __restrict__ y,
                                const int* __restrict__ uids, const int* __restrict__ iids,
                                float* __restrict__ uacc, float* __restrict__ iacc,
                                int batch, int num_users) {
    int t = blockIdx.x * blockDim.x + threadIdx.x;
    if (t >= batch * 16) return;
    int b = t >> 4;
    int q = t & 15;
    const float4* y4 = (const float4*)y;
    float4 u = y4[(long)uids[b] * 16 + q];
    float4 v = y4[((long)num_users + iids[b]) * 16 + q];
    float4* ua = (float4*)uacc;
    float4* ia = (float4*)iacc;
    float4 a = ua[t];
    a.x += u.x; a.y += u.y; a.z += u.z; a.w += u.w;
    ua[t] = a;
    float4 c = ia[t];
    c.x += v.x; c.y += v.y; c.z += v.z; c.w += v.w;
    ia[t] = c;
}

// ---------- scoring ----------
__global__ void score_kernel(const float* __restrict__ uacc, const float* __restrict__ iacc,
                             float* __restrict__ out, int batch) {
    int lane = threadIdx.x & 63;
    int w = (blockIdx.x * blockDim.x + threadIdx.x) >> 6;
    if (w >= batch) return;
    float p = uacc[(long)w * EMBED_DIM + lane] * iacc[(long)w * EMBED_DIM + lane];
    #pragma unroll
    for (int off = 32; off > 0; off >>= 1) p += __shfl_down(p, off);
    if (lane == 0) out[w] = p * (1.0f / 16.0f);  // (acc/4)·(acc/4)
}

extern "C" void kernel_launch(void* const* d_in, const int* in_sizes, int n_in,
                              void* d_out, int out_size, void* d_ws, size_t ws_size,
                              hipStream_t stream) {
    const float* user_emb = (const float*)d_in[0];
    const float* item_emb = (const float*)d_in[1];
    const int*   adj_rows = (const int*)d_in[2];
    const int*   adj_cols = (const int*)d_in[3];
    const float* adj_vals = (const float*)d_in[4];
    const int*   user_ids = (const int*)d_in[5];
    const int*   item_ids = (const int*)d_in[6];
    float* out = (float*)d_out;

    const int num_users = in_sizes[0] / EMBED_DIM;   // 200000
    const int num_items = in_sizes[1] / EMBED_DIM;   // 100000
    const int n_nodes   = num_users + num_items;     // 300000
    const int nnz       = in_sizes[2];               // 6000000
    const int batch     = in_sizes[5];               // 16384

    const long node_elems = (long)n_nodes * EMBED_DIM;    // 19.2M floats
    const long bacc_elems = (long)batch * EMBED_DIM;      // 1.05M floats

    const int nbuck = (n_nodes + BUCKET_ROWS - 1) >> BUCKET_SHIFT;   // 586
    const int nscan = nbuck * NBLK_A;                                // 150016
    const int nscan_blocks = (nscan + SCAN2_CHUNK - 1) / SCAN2_CHUNK; // 74

    // ---- workspace layout ----
    char* wp = (char*)d_ws;
    float* bufA = (float*)wp;            wp += node_elems * sizeof(float);
    float* bufB = (float*)wp;            wp += node_elems * sizeof(float);
    float* uacc = (float*)wp;            wp += bacc_elems * sizeof(float);
    float* iacc = (float*)wp;            wp += bacc_elems * sizeof(float);
    int*   row_ptr = (int*)wp;           wp += (size_t)(n_nodes + 1) * sizeof(int);
    int*   bsum    = (int*)wp;           wp += 512 * sizeof(int);
    int*   boff    = (int*)wp;           wp += 512 * sizeof(int);
    wp = (char*)(((uintptr_t)wp + 15) & ~(uintptr_t)15);
    int2*  perm    = (int2*)wp;          wp += (size_t)nnz * sizeof(int2);

    // overlays (dead before their regions are first written by the layer loop):
    // smeta staging lives in bufA (48 MB of 76.8; bufA first written by layer-1
    // spmm, after bucket_build). blockCounts/scanOut live in bufB (first written
    // by layer-2 spmm).
    int2* smeta       = (int2*)bufA;                              // nnz int2 (48 MB)
    int*  blockCounts = (int*)bufB;                               // nscan ints
    int*  scanOut     = blockCounts + nscan;                      // nscan ints

    // chunk rounded to 1024 so every block's range is int4-aligned and tail-free
    const int chunkA = (((nnz + NBLK_A - 1) / NBLK_A) + 1023) & ~1023;   // 24576

    // ---- radix CSR build (no device atomics) ----
    bucket_count_kernel<<<NBLK_A, 256, 0, stream>>>(adj_rows, blockCounts, nnz, nbuck, chunkA);
    scan8_phase1<<<nscan_blocks, 256, 0, stream>>>(blockCounts, bsum, nscan);
    scan_phase2<<<1, 512, 0, stream>>>(bsum, boff, nscan_blocks);
    scan8_phase3<<<nscan_blocks, 256, 0, stream>>>(blockCounts, boff, scanOut, nscan);
    bucket_scatter_kernel<<<NBLK_A, 256, 0, stream>>>(adj_rows, adj_cols, adj_vals,
                                                      scanOut, smeta, nnz, nbuck, chunkA);
    bucket_build_kernel<<<nbuck, 256, 0, stream>>>(smeta, scanOut, perm,
                                                   row_ptr, nnz, n_nodes, nbuck);

    // ---- batch accumulator init (layer-0 term) ----
    {
        int blocks = (batch * 16 + 255) / 256;
        init_bacc_kernel<<<blocks, 256, 0, stream>>>(user_emb, item_emb, user_ids, item_ids,
                                                     uacc, iacc, batch);
    }

    const int spmm_blocks = ((n_nodes * 64) + 255) / 256;   // one wave per row
    const int bblocks = (batch * 16 + 255) / 256;

    // ---- layer 1: concat(user_emb, item_emb) -> bufA ----
    spmm_csr_kernel<<<spmm_blocks, 256, 0, stream>>>(
        row_ptr, perm,
        user_emb, item_emb - (long)num_users * EMBED_DIM, num_users,
        bufA, n_nodes);
    bacc_add_kernel<<<bblocks, 256, 0, stream>>>(bufA, user_ids, item_ids,
                                                 uacc, iacc, batch, num_users);

    // ---- layer 2: bufA -> bufB ----
    spmm_csr_kernel<<<spmm_blocks, 256, 0, stream>>>(
        row_ptr, perm, bufA, bufA, 0x7fffffff, bufB, n_nodes);
    bacc_add_kernel<<<bblocks, 256, 0, stream>>>(bufB, user_ids, item_ids,
                                                 uacc, iacc, batch, num_users);

    // ---- layer 3: bufB -> bufA ----
    spmm_csr_kernel<<<spmm_blocks, 256, 0, stream>>>(
        row_ptr, perm, bufB, bufB, 0x7fffffff, bufA, n_nodes);
    bacc_add_kernel<<<bblocks, 256, 0, stream>>>(bufA, user_ids, item_ids,
                                                 uacc, iacc, batch, num_users);

    // ---- score ----
    {
        int blocks = (batch * 64 + 255) / 256;
        score_kernel<<<blocks, 256, 0, stream>>>(uacc, iacc, out, batch);
    }
}

// Round 8
// 686.745 us; speedup vs baseline: 5.4906x; 1.2819x over previous
//
#include <hip/hip_runtime.h>

#define EMBED_DIM 64
#define NBLK_A 256            // blocks in bucket count/scatter passes
#define BUCKET_SHIFT 9        // 512 rows per bucket
#define BUCKET_ROWS 512
#define MAX_NBUCK 640
#define SCAN2_CHUNK 2048      // 256 threads x 8
#define COL_BITS 19           // col < 2^19; meta = (localrow << 19) | col

typedef float fx4 __attribute__((ext_vector_type(4)));

// ---------- pass A1: per-block bucket histogram (LDS), bucket-major dump ----------
__global__ __launch_bounds__(256) void bucket_count_kernel(
    const int* __restrict__ rows, int* __restrict__ blockCounts,
    int nnz, int nbuck, int chunk) {
    __shared__ int hist[MAX_NBUCK];
    int t = threadIdx.x, blk = blockIdx.x;
    for (int i = t; i < nbuck; i += 256) hist[i] = 0;
    __syncthreads();
    int e0 = blk * chunk;
    int e1 = min(e0 + chunk, nnz);
    for (int e = e0 + t * 4; e < e1; e += 1024) {
        int4 r4 = *reinterpret_cast<const int4*>(rows + e);
        atomicAdd(&hist[r4.x >> BUCKET_SHIFT], 1);
        atomicAdd(&hist[r4.y >> BUCKET_SHIFT], 1);
        atomicAdd(&hist[r4.z >> BUCKET_SHIFT], 1);
        atomicAdd(&hist[r4.w >> BUCKET_SHIFT], 1);
    }
    __syncthreads();
    for (int u = t; u < nbuck; u += 256)
        blockCounts[u * NBLK_A + blk] = hist[u];
}

// ---------- scan phase 1 (chunk 2048): per-block sums ----------
__global__ void scan8_phase1(const int* __restrict__ in, int* __restrict__ bsum, int n) {
    __shared__ int wsum[4];
    int t = threadIdx.x, b = blockIdx.x;
    int i0 = b * SCAN2_CHUNK + t * 8;
    int s = 0;
    #pragma unroll
    for (int k = 0; k < 8; ++k) { int i = i0 + k; if (i < n) s += in[i]; }
    #pragma unroll
    for (int off = 1; off < 64; off <<= 1) s += __shfl_xor(s, off);
    if ((t & 63) == 0) wsum[t >> 6] = s;
    __syncthreads();
    if (t == 0) bsum[b] = wsum[0] + wsum[1] + wsum[2] + wsum[3];
}

// ---------- scan phase 2: single-block scan of block sums (nb <= 512) ----------
__global__ void scan_phase2(const int* __restrict__ bsum, int* __restrict__ boff, int nb) {
    __shared__ int lds[512];
    int t = threadIdx.x;
    lds[t] = (t < nb) ? bsum[t] : 0;
    __syncthreads();
    for (int off = 1; off < 512; off <<= 1) {
        int v = (t >= off) ? lds[t - off] : 0;
        __syncthreads();
        lds[t] += v;
        __syncthreads();
    }
    if (t < nb) boff[t] = (t == 0) ? 0 : lds[t - 1];
}

// ---------- scan phase 3 (chunk 2048): write exclusive prefix ----------
__global__ void scan8_phase3(const int* __restrict__ in, const int* __restrict__ boff,
                             int* __restrict__ out, int n) {
    __shared__ int wexcl[4];
    int t = threadIdx.x, b = blockIdx.x;
    int lane = t & 63, w = t >> 6;
    int i0 = b * SCAN2_CHUNK + t * 8;
    int c[8];
    int s = 0;
    #pragma unroll
    for (int k = 0; k < 8; ++k) { int i = i0 + k; c[k] = (i < n) ? in[i] : 0; s += c[k]; }
    int incl = s;
    #pragma unroll
    for (int off = 1; off < 64; off <<= 1) {
        int u = __shfl_up(incl, off);
        if (lane >= off) incl += u;
    }
    if (lane == 63) wexcl[w] = incl;
    __syncthreads();
    int wbase = 0;
    for (int ww = 0; ww < w; ++ww) wbase += wexcl[ww];
    int run = incl - s + wbase + boff[b];
    #pragma unroll
    for (int k = 0; k < 8; ++k) {
        int i = i0 + k;
        if (i < n) { out[i] = run; run += c[k]; }
    }
}

// ---------- pass A3: scatter edges into bucket-partitioned staging (LDS cursors) ----------
__global__ __launch_bounds__(256) void bucket_scatter_kernel(
    const int* __restrict__ rows, const int* __restrict__ cols,
    const float* __restrict__ vals, const int* __restrict__ scanOut,
    int2* __restrict__ smeta, int nnz, int nbuck, int chunk) {
    __shared__ int cur[MAX_NBUCK];
    int t = threadIdx.x, blk = blockIdx.x;
    for (int u = t; u < nbuck; u += 256) cur[u] = scanOut[u * NBLK_A + blk];
    __syncthreads();
    int e0 = blk * chunk;
    int e1 = min(e0 + chunk, nnz);
    for (int e = e0 + t * 4; e < e1; e += 1024) {
        int4   r4 = *reinterpret_cast<const int4*>(rows + e);
        int4   c4 = *reinterpret_cast<const int4*>(cols + e);
        float4 v4 = *reinterpret_cast<const float4*>(vals + e);
        int p0 = atomicAdd(&cur[r4.x >> BUCKET_SHIFT], 1);
        smeta[p0] = make_int2(((r4.x & (BUCKET_ROWS - 1)) << COL_BITS) | c4.x, __float_as_int(v4.x));
        int p1 = atomicAdd(&cur[r4.y >> BUCKET_SHIFT], 1);
        smeta[p1] = make_int2(((r4.y & (BUCKET_ROWS - 1)) << COL_BITS) | c4.y, __float_as_int(v4.y));
        int p2 = atomicAdd(&cur[r4.z >> BUCKET_SHIFT], 1);
        smeta[p2] = make_int2(((r4.z & (BUCKET_ROWS - 1)) << COL_BITS) | c4.z, __float_as_int(v4.z));
        int p3 = atomicAdd(&cur[r4.w >> BUCKET_SHIFT], 1);
        smeta[p3] = make_int2(((r4.w & (BUCKET_ROWS - 1)) << COL_BITS) | c4.w, __float_as_int(v4.w));
    }
}

// ---------- pass B: per-bucket counting sort -> row_ptr + perm ----------
__global__ __launch_bounds__(256) void bucket_build_kernel(
    const int2* __restrict__ smeta, const int* __restrict__ scanOut,
    int2* __restrict__ perm, int* __restrict__ row_ptr,
    int nnz, int n_nodes, int nbuck) {
    __shared__ int hist[BUCKET_ROWS], excl[BUCKET_ROWS], cur[BUCKET_ROWS];
    __shared__ int wex[4];
    int t = threadIdx.x, b = blockIdx.x;
    int lane = t & 63, w = t >> 6;
    int ebeg = scanOut[b * NBLK_A];
    int eend = (b + 1 < nbuck) ? scanOut[(b + 1) * NBLK_A] : nnz;
    hist[t] = 0; hist[t + 256] = 0;
    __syncthreads();
    for (int e = ebeg + t; e < eend; e += 256)
        atomicAdd(&hist[smeta[e].x >> COL_BITS], 1);
    __syncthreads();
    int a = hist[2 * t], bcnt = hist[2 * t + 1];
    int s = a + bcnt;
    int incl = s;
    #pragma unroll
    for (int off = 1; off < 64; off <<= 1) {
        int u = __shfl_up(incl, off);
        if (lane >= off) incl += u;
    }
    if (lane == 63) wex[w] = incl;
    __syncthreads();
    int wbase = 0;
    for (int ww = 0; ww < w; ++ww) wbase += wex[ww];
    int es = wbase + incl - s;
    excl[2 * t] = es;
    excl[2 * t + 1] = es + a;
    cur[2 * t] = es;
    cur[2 * t + 1] = es + a;
    __syncthreads();
    int base_row = b << BUCKET_SHIFT;
    for (int r = t; r < BUCKET_ROWS; r += 256) {
        int gr = base_row + r;
        if (gr < n_nodes) row_ptr[gr] = ebeg + excl[r];
    }
    if (b == 0 && t == 0) row_ptr[n_nodes] = nnz;
    for (int e = ebeg + t; e < eend; e += 256) {
        int2 m = smeta[e];
        int l = m.x >> COL_BITS;
        int p = atomicAdd(&cur[l], 1);
        perm[ebeg + p] = make_int2(m.x & ((1 << COL_BITS) - 1), m.y);
    }
}

// ---------- batch accumulator init (float4) ----------
__global__ void init_bacc_kernel(const float* __restrict__ ue, const float* __restrict__ ie,
                                 const int* __restrict__ uids, const int* __restrict__ iids,
                                 float* __restrict__ uacc, float* __restrict__ iacc, int batch) {
    int t = blockIdx.x * blockDim.x + threadIdx.x;
    if (t >= batch * 16) return;
    int b = t >> 4;
    int q = t & 15;
    const float4* ue4 = (const float4*)ue;
    const float4* ie4 = (const float4*)ie;
    ((float4*)uacc)[t] = ue4[(long)uids[b] * 16 + q];
    ((float4*)iacc)[t] = ie4[(long)iids[b] * 16 + q];
}

// ---------- CSR gather SpMM: one wave per row, 8 edges x float4 per iteration ----------
__global__ __launch_bounds__(256) void spmm_csr_kernel(
    const int* __restrict__ row_ptr, const int2* __restrict__ perm,
    const float* __restrict__ xu, const float* __restrict__ xi_off, int nu,
    float* __restrict__ y, int n_nodes) {
    int lane = threadIdx.x & 63;
    int row = (blockIdx.x * blockDim.x + threadIdx.x) >> 6;
    if (row >= n_nodes) return;
    int start = row_ptr[row];
    int end   = row_ptr[row + 1];
    int sub  = lane >> 4;    // edge slot 0..3
    int dimq = lane & 15;    // float4 index within the 64-dim row
    fx4 acc0 = (fx4)(0.f);
    fx4 acc1 = (fx4)(0.f);
    for (int base = start; base < end; base += 8) {
        int e0 = base + sub;
        int e1 = e0 + 4;
        int2 p0 = make_int2(0, 0);
        int2 p1 = make_int2(0, 0);
        if (e0 < end) p0 = perm[e0];
        if (e1 < end) p1 = perm[e1];
        float v0 = __int_as_float(p0.y);
        float v1 = __int_as_float(p1.y);
        const float* xr0 = (p0.x < nu) ? (xu + (long)p0.x * EMBED_DIM)
                                       : (xi_off + (long)p0.x * EMBED_DIM);
        const float* xr1 = (p1.x < nu) ? (xu + (long)p1.x * EMBED_DIM)
                                       : (xi_off + (long)p1.x * EMBED_DIM);
        fx4 xv0 = reinterpret_cast<const fx4*>(xr0)[dimq];
        fx4 xv1 = reinterpret_cast<const fx4*>(xr1)[dimq];
        acc0.x = fmaf(v0, xv0.x, acc0.x);
        acc0.y = fmaf(v0, xv0.y, acc0.y);
        acc0.z = fmaf(v0, xv0.z, acc0.z);
        acc0.w = fmaf(v0, xv0.w, acc0.w);
        acc1.x = fmaf(v1, xv1.x, acc1.x);
        acc1.y = fmaf(v1, xv1.y, acc1.y);
        acc1.z = fmaf(v1, xv1.z, acc1.z);
        acc1.w = fmaf(v1, xv1.w, acc1.w);
    }
    fx4 acc;
    acc.x = acc0.x + acc1.x;
    acc.y = acc0.y + acc1.y;
    acc.z = acc0.z + acc1.z;
    acc.w = acc0.w + acc1.w;
    #pragma unroll
    for (int off = 16; off < 64; off <<= 1) {
        acc.x += __shfl_xor(acc.x, off);
        acc.y += __shfl_xor(acc.y, off);
        acc.z += __shfl_xor(acc.z, off);
        acc.w += __shfl_xor(acc.w, off);
    }
    if (sub == 0) {
        reinterpret_cast<fx4*>(y + (long)row * EMBED_DIM)[dimq] = acc;
    }
}

// ---------- layer-3 batch-restricted SpMM: one wave per batch slot ----------
// Computes y3[row] for row = uid[slot] (or NU+iid[slot]) and accumulates it
// directly into uacc/iacc[slot]. Duplicate ids occupy distinct slots -> no race.
__global__ __launch_bounds__(256) void spmm_batch_kernel(
    const int* __restrict__ row_ptr, const int2* __restrict__ perm,
    const float* __restrict__ x,
    const int* __restrict__ uids, const int* __restrict__ iids,
    float* __restrict__ uacc, float* __restrict__ iacc,
    int batch, int num_users) {
    int lane = threadIdx.x & 63;
    int w = (blockIdx.x * blockDim.x + threadIdx.x) >> 6;
    if (w >= 2 * batch) return;
    int row;
    float* target;
    if (w < batch) { row = uids[w];                target = uacc + (long)w * EMBED_DIM; }
    else           { row = num_users + iids[w - batch]; target = iacc + (long)(w - batch) * EMBED_DIM; }
    int start = row_ptr[row];
    int end   = row_ptr[row + 1];
    int sub  = lane >> 4;
    int dimq = lane & 15;
    fx4 acc0 = (fx4)(0.f);
    fx4 acc1 = (fx4)(0.f);
    for (int base = start; base < end; base += 8) {
        int e0 = base + sub;
        int e1 = e0 + 4;
        int2 p0 = make_int2(0, 0);
        int2 p1 = make_int2(0, 0);
        if (e0 < end) p0 = perm[e0];
        if (e1 < end) p1 = perm[e1];
        float v0 = __int_as_float(p0.y);
        float v1 = __int_as_float(p1.y);
        fx4 xv0 = reinterpret_cast<const fx4*>(x + (long)p0.x * EMBED_DIM)[dimq];
        fx4 xv1 = reinterpret_cast<const fx4*>(x + (long)p1.x * EMBED_DIM)[dimq];
        acc0.x = fmaf(v0, xv0.x, acc0.x);
        acc0.y = fmaf(v0, xv0.y, acc0.y);
        acc0.z = fmaf(v0, xv0.z, acc0.z);
        acc0.w = fmaf(v0, xv0.w, acc0.w);
        acc1.x = fmaf(v1, xv1.x, acc1.x);
        acc1.y = fmaf(v1, xv1.y, acc1.y);
        acc1.z = fmaf(v1, xv1.z, acc1.z);
        acc1.w = fmaf(v1, xv1.w, acc1.w);
    }
    fx4 acc;
    acc.x = acc0.x + acc1.x;
    acc.y = acc0.y + acc1.y;
    acc.z = acc0.z + acc1.z;
    acc.w = acc0.w + acc1.w;
    #pragma unroll
    for (int off = 16; off < 64; off <<= 1) {
        acc.x += __shfl_xor(acc.x, off);
        acc.y += __shfl_xor(acc.y, off);
        acc.z += __shfl_xor(acc.z, off);
        acc.w += __shfl_xor(acc.w, off);
    }
    if (sub == 0) {
        fx4* t4 = reinterpret_cast<fx4*>(target);
        fx4 old = t4[dimq];
        old.x += acc.x; old.y += acc.y; old.z += acc.z; old.w += acc.w;
        t4[dimq] = old;
    }
}

// ---------- per-layer batch accumulate (float4) ----------
__global__ void bacc_add_kernel(const float* __restrict__ y,
                                const int* __restrict__ uids, const int* __restrict__ iids,
                                float* __restrict__ uacc, float* __restrict__ iacc,
                                int batch, int num_users) {
    int t = blockIdx.x * blockDim.x + threadIdx.x;
    if (t >= batch * 16) return;
    int b = t >> 4;
    int q = t & 15;
    const float4* y4 = (const float4*)y;
    float4 u = y4[(long)uids[b] * 16 + q];
    float4 v = y4[((long)num_users + iids[b]) * 16 + q];
    float4* ua = (float4*)uacc;
    float4* ia = (float4*)iacc;
    float4 a = ua[t];
    a.x += u.x; a.y += u.y; a.z += u.z; a.w += u.w;
    ua[t] = a;
    float4 c = ia[t];
    c.x += v.x; c.y += v.y; c.z += v.z; c.w += v.w;
    ia[t] = c;
}

// ---------- scoring ----------
__global__ void score_kernel(const float* __restrict__ uacc, const float* __restrict__ iacc,
                             float* __restrict__ out, int batch) {
    int lane = threadIdx.x & 63;
    int w = (blockIdx.x * blockDim.x + threadIdx.x) >> 6;
    if (w >= batch) return;
    float p = uacc[(long)w * EMBED_DIM + lane] * iacc[(long)w * EMBED_DIM + lane];
    #pragma unroll
    for (int off = 32; off > 0; off >>= 1) p += __shfl_down(p, off);
    if (lane == 0) out[w] = p * (1.0f / 16.0f);  // (acc/4)·(acc/4)
}

extern "C" void kernel_launch(void* const* d_in, const int* in_sizes, int n_in,
                              void* d_out, int out_size, void* d_ws, size_t ws_size,
                              hipStream_t stream) {
    const float* user_emb = (const float*)d_in[0];
    const float* item_emb = (const float*)d_in[1];
    const int*   adj_rows = (const int*)d_in[2];
    const int*   adj_cols = (const int*)d_in[3];
    const float* adj_vals = (const float*)d_in[4];
    const int*   user_ids = (const int*)d_in[5];
    const int*   item_ids = (const int*)d_in[6];
    float* out = (float*)d_out;

    const int num_users = in_sizes[0] / EMBED_DIM;   // 200000
    const int num_items = in_sizes[1] / EMBED_DIM;   // 100000
    const int n_nodes   = num_users + num_items;     // 300000
    const int nnz       = in_sizes[2];               // 6000000
    const int batch     = in_sizes[5];               // 16384

    const long node_elems = (long)n_nodes * EMBED_DIM;    // 19.2M floats
    const long bacc_elems = (long)batch * EMBED_DIM;      // 1.05M floats

    const int nbuck = (n_nodes + BUCKET_ROWS - 1) >> BUCKET_SHIFT;   // 586
    const int nscan = nbuck * NBLK_A;                                // 150016
    const int nscan_blocks = (nscan + SCAN2_CHUNK - 1) / SCAN2_CHUNK; // 74

    // ---- workspace layout ----
    char* wp = (char*)d_ws;
    float* bufA = (float*)wp;            wp += node_elems * sizeof(float);
    float* bufB = (float*)wp;            wp += node_elems * sizeof(float);
    float* uacc = (float*)wp;            wp += bacc_elems * sizeof(float);
    float* iacc = (float*)wp;            wp += bacc_elems * sizeof(float);
    int*   row_ptr = (int*)wp;           wp += (size_t)(n_nodes + 1) * sizeof(int);
    int*   bsum    = (int*)wp;           wp += 512 * sizeof(int);
    int*   boff    = (int*)wp;           wp += 512 * sizeof(int);
    wp = (char*)(((uintptr_t)wp + 15) & ~(uintptr_t)15);
    int2*  perm    = (int2*)wp;          wp += (size_t)nnz * sizeof(int2);

    // overlays (dead before their regions are first written by the layer loop)
    int2* smeta       = (int2*)bufA;                              // nnz int2 (48 MB)
    int*  blockCounts = (int*)bufB;                               // nscan ints
    int*  scanOut     = blockCounts + nscan;                      // nscan ints

    const int chunkA = (((nnz + NBLK_A - 1) / NBLK_A) + 1023) & ~1023;   // 24576

    // ---- radix CSR build (no device atomics) ----
    bucket_count_kernel<<<NBLK_A, 256, 0, stream>>>(adj_rows, blockCounts, nnz, nbuck, chunkA);
    scan8_phase1<<<nscan_blocks, 256, 0, stream>>>(blockCounts, bsum, nscan);
    scan_phase2<<<1, 512, 0, stream>>>(bsum, boff, nscan_blocks);
    scan8_phase3<<<nscan_blocks, 256, 0, stream>>>(blockCounts, boff, scanOut, nscan);
    bucket_scatter_kernel<<<NBLK_A, 256, 0, stream>>>(adj_rows, adj_cols, adj_vals,
                                                      scanOut, smeta, nnz, nbuck, chunkA);
    bucket_build_kernel<<<nbuck, 256, 0, stream>>>(smeta, scanOut, perm,
                                                   row_ptr, nnz, n_nodes, nbuck);

    // ---- batch accumulator init (layer-0 term) ----
    {
        int blocks = (batch * 16 + 255) / 256;
        init_bacc_kernel<<<blocks, 256, 0, stream>>>(user_emb, item_emb, user_ids, item_ids,
                                                     uacc, iacc, batch);
    }

    const int spmm_blocks = ((n_nodes * 64) + 255) / 256;   // one wave per row
    const int bblocks = (batch * 16 + 255) / 256;

    // ---- layer 1: concat(user_emb, item_emb) -> bufA ----
    spmm_csr_kernel<<<spmm_blocks, 256, 0, stream>>>(
        row_ptr, perm,
        user_emb, item_emb - (long)num_users * EMBED_DIM, num_users,
        bufA, n_nodes);
    bacc_add_kernel<<<bblocks, 256, 0, stream>>>(bufA, user_ids, item_ids,
                                                 uacc, iacc, batch, num_users);

    // ---- layer 2: bufA -> bufB ----
    spmm_csr_kernel<<<spmm_blocks, 256, 0, stream>>>(
        row_ptr, perm, bufA, bufA, 0x7fffffff, bufB, n_nodes);
    bacc_add_kernel<<<bblocks, 256, 0, stream>>>(bufB, user_ids, item_ids,
                                                 uacc, iacc, batch, num_users);

    // ---- layer 3 (batch-restricted): bufB -> uacc/iacc directly ----
    {
        int waves = 2 * batch;                        // 32768 waves
        int blocks = (waves * 64 + 255) / 256;        // 8192 blocks
        spmm_batch_kernel<<<blocks, 256, 0, stream>>>(row_ptr, perm, bufB,
                                                      user_ids, item_ids,
                                                      uacc, iacc, batch, num_users);
    }

    // ---- score ----
    {
        int blocks = (batch * 64 + 255) / 256;
        score_kernel<<<blocks, 256, 0, stream>>>(uacc, iacc, out, batch);
    }
}

// Round 9
// 507.843 us; speedup vs baseline: 7.4248x; 1.3523x over previous
//
#include <hip/hip_runtime.h>

#define EMBED_DIM 64
#define NBLK_A 256            // blocks in bucket count/scatter passes
#define BUCKET_SHIFT 9        // 512 rows per bucket
#define BUCKET_ROWS 512
#define MAX_NBUCK 640
#define SCAN2_CHUNK 2048      // 256 threads x 8
#define COL_BITS 19           // col < 2^19; meta = (localrow << 19) | col

typedef float fx4 __attribute__((ext_vector_type(4)));
typedef _Float16 h8v __attribute__((ext_vector_type(8)));

// ---------- convert concat(user_emb, item_emb) fp32 -> fp16 ----------
__global__ void convert_x_kernel(const float* __restrict__ ue, const float* __restrict__ ie,
                                 _Float16* __restrict__ xh, int nu_elems, int total) {
    int i = blockIdx.x * blockDim.x + threadIdx.x;   // index in units of 8 elems
    int stride = gridDim.x * blockDim.x;
    int n8 = total >> 3;
    int nu8 = nu_elems >> 3;
    for (; i < n8; i += stride) {
        const float4* src = (i < nu8) ? (const float4*)(ue) + 2 * i
                                      : (const float4*)(ie) + 2 * (i - nu8);
        float4 lo = src[0];
        float4 hi = src[1];
        h8v o;
        o[0] = (_Float16)lo.x; o[1] = (_Float16)lo.y;
        o[2] = (_Float16)lo.z; o[3] = (_Float16)lo.w;
        o[4] = (_Float16)hi.x; o[5] = (_Float16)hi.y;
        o[6] = (_Float16)hi.z; o[7] = (_Float16)hi.w;
        reinterpret_cast<h8v*>(xh)[i] = o;
    }
}

// ---------- pass A1: per-block bucket histogram (LDS), bucket-major dump ----------
__global__ __launch_bounds__(256) void bucket_count_kernel(
    const int* __restrict__ rows, int* __restrict__ blockCounts,
    int nnz, int nbuck, int chunk) {
    __shared__ int hist[MAX_NBUCK];
    int t = threadIdx.x, blk = blockIdx.x;
    for (int i = t; i < nbuck; i += 256) hist[i] = 0;
    __syncthreads();
    int e0 = blk * chunk;
    int e1 = min(e0 + chunk, nnz);
    for (int e = e0 + t * 4; e < e1; e += 1024) {
        int4 r4 = *reinterpret_cast<const int4*>(rows + e);
        atomicAdd(&hist[r4.x >> BUCKET_SHIFT], 1);
        atomicAdd(&hist[r4.y >> BUCKET_SHIFT], 1);
        atomicAdd(&hist[r4.z >> BUCKET_SHIFT], 1);
        atomicAdd(&hist[r4.w >> BUCKET_SHIFT], 1);
    }
    __syncthreads();
    for (int u = t; u < nbuck; u += 256)
        blockCounts[u * NBLK_A + blk] = hist[u];
}

// ---------- scan phase 1 (chunk 2048): per-block sums ----------
__global__ void scan8_phase1(const int* __restrict__ in, int* __restrict__ bsum, int n) {
    __shared__ int wsum[4];
    int t = threadIdx.x, b = blockIdx.x;
    int i0 = b * SCAN2_CHUNK + t * 8;
    int s = 0;
    #pragma unroll
    for (int k = 0; k < 8; ++k) { int i = i0 + k; if (i < n) s += in[i]; }
    #pragma unroll
    for (int off = 1; off < 64; off <<= 1) s += __shfl_xor(s, off);
    if ((t & 63) == 0) wsum[t >> 6] = s;
    __syncthreads();
    if (t == 0) bsum[b] = wsum[0] + wsum[1] + wsum[2] + wsum[3];
}

// ---------- scan phase 2: single-block scan of block sums (nb <= 512) ----------
__global__ void scan_phase2(const int* __restrict__ bsum, int* __restrict__ boff, int nb) {
    __shared__ int lds[512];
    int t = threadIdx.x;
    lds[t] = (t < nb) ? bsum[t] : 0;
    __syncthreads();
    for (int off = 1; off < 512; off <<= 1) {
        int v = (t >= off) ? lds[t - off] : 0;
        __syncthreads();
        lds[t] += v;
        __syncthreads();
    }
    if (t < nb) boff[t] = (t == 0) ? 0 : lds[t - 1];
}

// ---------- scan phase 3 (chunk 2048): write exclusive prefix ----------
__global__ void scan8_phase3(const int* __restrict__ in, const int* __restrict__ boff,
                             int* __restrict__ out, int n) {
    __shared__ int wexcl[4];
    int t = threadIdx.x, b = blockIdx.x;
    int lane = t & 63, w = t >> 6;
    int i0 = b * SCAN2_CHUNK + t * 8;
    int c[8];
    int s = 0;
    #pragma unroll
    for (int k = 0; k < 8; ++k) { int i = i0 + k; c[k] = (i < n) ? in[i] : 0; s += c[k]; }
    int incl = s;
    #pragma unroll
    for (int off = 1; off < 64; off <<= 1) {
        int u = __shfl_up(incl, off);
        if (lane >= off) incl += u;
    }
    if (lane == 63) wexcl[w] = incl;
    __syncthreads();
    int wbase = 0;
    for (int ww = 0; ww < w; ++ww) wbase += wexcl[ww];
    int run = incl - s + wbase + boff[b];
    #pragma unroll
    for (int k = 0; k < 8; ++k) {
        int i = i0 + k;
        if (i < n) { out[i] = run; run += c[k]; }
    }
}

// ---------- pass A3: scatter edges into bucket-partitioned staging (LDS cursors) ----------
__global__ __launch_bounds__(256) void bucket_scatter_kernel(
    const int* __restrict__ rows, const int* __restrict__ cols,
    const float* __restrict__ vals, const int* __restrict__ scanOut,
    int2* __restrict__ smeta, int nnz, int nbuck, int chunk) {
    __shared__ int cur[MAX_NBUCK];
    int t = threadIdx.x, blk = blockIdx.x;
    for (int u = t; u < nbuck; u += 256) cur[u] = scanOut[u * NBLK_A + blk];
    __syncthreads();
    int e0 = blk * chunk;
    int e1 = min(e0 + chunk, nnz);
    for (int e = e0 + t * 4; e < e1; e += 1024) {
        int4   r4 = *reinterpret_cast<const int4*>(rows + e);
        int4   c4 = *reinterpret_cast<const int4*>(cols + e);
        float4 v4 = *reinterpret_cast<const float4*>(vals + e);
        int p0 = atomicAdd(&cur[r4.x >> BUCKET_SHIFT], 1);
        smeta[p0] = make_int2(((r4.x & (BUCKET_ROWS - 1)) << COL_BITS) | c4.x, __float_as_int(v4.x));
        int p1 = atomicAdd(&cur[r4.y >> BUCKET_SHIFT], 1);
        smeta[p1] = make_int2(((r4.y & (BUCKET_ROWS - 1)) << COL_BITS) | c4.y, __float_as_int(v4.y));
        int p2 = atomicAdd(&cur[r4.z >> BUCKET_SHIFT], 1);
        smeta[p2] = make_int2(((r4.z & (BUCKET_ROWS - 1)) << COL_BITS) | c4.z, __float_as_int(v4.z));
        int p3 = atomicAdd(&cur[r4.w >> BUCKET_SHIFT], 1);
        smeta[p3] = make_int2(((r4.w & (BUCKET_ROWS - 1)) << COL_BITS) | c4.w, __float_as_int(v4.w));
    }
}

// ---------- pass B: per-bucket counting sort -> row_ptr + perm ----------
__global__ __launch_bounds__(256) void bucket_build_kernel(
    const int2* __restrict__ smeta, const int* __restrict__ scanOut,
    int2* __restrict__ perm, int* __restrict__ row_ptr,
    int nnz, int n_nodes, int nbuck) {
    __shared__ int hist[BUCKET_ROWS], excl[BUCKET_ROWS], cur[BUCKET_ROWS];
    __shared__ int wex[4];
    int t = threadIdx.x, b = blockIdx.x;
    int lane = t & 63, w = t >> 6;
    int ebeg = scanOut[b * NBLK_A];
    int eend = (b + 1 < nbuck) ? scanOut[(b + 1) * NBLK_A] : nnz;
    hist[t] = 0; hist[t + 256] = 0;
    __syncthreads();
    for (int e = ebeg + t; e < eend; e += 256)
        atomicAdd(&hist[smeta[e].x >> COL_BITS], 1);
    __syncthreads();
    int a = hist[2 * t], bcnt = hist[2 * t + 1];
    int s = a + bcnt;
    int incl = s;
    #pragma unroll
    for (int off = 1; off < 64; off <<= 1) {
        int u = __shfl_up(incl, off);
        if (lane >= off) incl += u;
    }
    if (lane == 63) wex[w] = incl;
    __syncthreads();
    int wbase = 0;
    for (int ww = 0; ww < w; ++ww) wbase += wex[ww];
    int es = wbase + incl - s;
    excl[2 * t] = es;
    excl[2 * t + 1] = es + a;
    cur[2 * t] = es;
    cur[2 * t + 1] = es + a;
    __syncthreads();
    int base_row = b << BUCKET_SHIFT;
    for (int r = t; r < BUCKET_ROWS; r += 256) {
        int gr = base_row + r;
        if (gr < n_nodes) row_ptr[gr] = ebeg + excl[r];
    }
    if (b == 0 && t == 0) row_ptr[n_nodes] = nnz;
    for (int e = ebeg + t; e < eend; e += 256) {
        int2 m = smeta[e];
        int l = m.x >> COL_BITS;
        int p = atomicAdd(&cur[l], 1);
        perm[ebeg + p] = make_int2(m.x & ((1 << COL_BITS) - 1), m.y);
    }
}

// ---------- batch accumulator init (float4, from fp32 embeddings) ----------
__global__ void init_bacc_kernel(const float* __restrict__ ue, const float* __restrict__ ie,
                                 const int* __restrict__ uids, const int* __restrict__ iids,
                                 float* __restrict__ uacc, float* __restrict__ iacc, int batch) {
    int t = blockIdx.x * blockDim.x + threadIdx.x;
    if (t >= batch * 16) return;
    int b = t >> 4;
    int q = t & 15;
    const float4* ue4 = (const float4*)ue;
    const float4* ie4 = (const float4*)ie;
    ((float4*)uacc)[t] = ue4[(long)uids[b] * 16 + q];
    ((float4*)iacc)[t] = ie4[(long)iids[b] * 16 + q];
}

// ---------- fp16 CSR gather SpMM: one wave per row, 8 edge-slots x 8 dim-lanes ----------
// 16 edges per iteration (2 independent groups). fp32 accumulate, fp16 store.
__global__ __launch_bounds__(256) void spmm_csr_h_kernel(
    const int* __restrict__ row_ptr, const int2* __restrict__ perm,
    const _Float16* __restrict__ x, _Float16* __restrict__ y, int n_nodes) {
    int lane = threadIdx.x & 63;
    int row = (blockIdx.x * blockDim.x + threadIdx.x) >> 6;
    if (row >= n_nodes) return;
    int start = row_ptr[row];
    int end   = row_ptr[row + 1];
    int sub  = lane >> 3;    // edge slot 0..7
    int dimq = lane & 7;     // half8 index within the 64-dim row
    const h8v* x8 = reinterpret_cast<const h8v*>(x);
    float acc0[8], acc1[8];
    #pragma unroll
    for (int k = 0; k < 8; ++k) { acc0[k] = 0.f; acc1[k] = 0.f; }
    for (int base = start; base < end; base += 16) {
        int e0 = base + sub;
        int e1 = e0 + 8;
        int2 p0 = (e0 < end) ? perm[e0] : make_int2(0, 0);
        int2 p1 = (e1 < end) ? perm[e1] : make_int2(0, 0);
        float v0 = __int_as_float(p0.y);
        float v1 = __int_as_float(p1.y);
        h8v xv0 = x8[(long)p0.x * 8 + dimq];
        h8v xv1 = x8[(long)p1.x * 8 + dimq];
        #pragma unroll
        for (int k = 0; k < 8; ++k) acc0[k] = fmaf(v0, (float)xv0[k], acc0[k]);
        #pragma unroll
        for (int k = 0; k < 8; ++k) acc1[k] = fmaf(v1, (float)xv1[k], acc1[k]);
    }
    float accf[8];
    #pragma unroll
    for (int k = 0; k < 8; ++k) accf[k] = acc0[k] + acc1[k];
    #pragma unroll
    for (int off = 8; off < 64; off <<= 1) {
        #pragma unroll
        for (int k = 0; k < 8; ++k) accf[k] += __shfl_xor(accf[k], off);
    }
    if (sub == 0) {
        h8v o;
        #pragma unroll
        for (int k = 0; k < 8; ++k) o[k] = (_Float16)accf[k];
        reinterpret_cast<h8v*>(y)[(long)row * 8 + dimq] = o;
    }
}

// ---------- layer-3 batch-restricted SpMM (fp16 x), accumulate into fp32 acc ----------
__global__ __launch_bounds__(256) void spmm_batch_h_kernel(
    const int* __restrict__ row_ptr, const int2* __restrict__ perm,
    const _Float16* __restrict__ x,
    const int* __restrict__ uids, const int* __restrict__ iids,
    float* __restrict__ uacc, float* __restrict__ iacc,
    int batch, int num_users) {
    int lane = threadIdx.x & 63;
    int w = (blockIdx.x * blockDim.x + threadIdx.x) >> 6;
    if (w >= 2 * batch) return;
    int row;
    float* target;
    if (w < batch) { row = uids[w];                     target = uacc + (long)w * EMBED_DIM; }
    else           { row = num_users + iids[w - batch]; target = iacc + (long)(w - batch) * EMBED_DIM; }
    int start = row_ptr[row];
    int end   = row_ptr[row + 1];
    int sub  = lane >> 3;
    int dimq = lane & 7;
    const h8v* x8 = reinterpret_cast<const h8v*>(x);
    float acc0[8], acc1[8];
    #pragma unroll
    for (int k = 0; k < 8; ++k) { acc0[k] = 0.f; acc1[k] = 0.f; }
    for (int base = start; base < end; base += 16) {
        int e0 = base + sub;
        int e1 = e0 + 8;
        int2 p0 = (e0 < end) ? perm[e0] : make_int2(0, 0);
        int2 p1 = (e1 < end) ? perm[e1] : make_int2(0, 0);
        float v0 = __int_as_float(p0.y);
        float v1 = __int_as_float(p1.y);
        h8v xv0 = x8[(long)p0.x * 8 + dimq];
        h8v xv1 = x8[(long)p1.x * 8 + dimq];
        #pragma unroll
        for (int k = 0; k < 8; ++k) acc0[k] = fmaf(v0, (float)xv0[k], acc0[k]);
        #pragma unroll
        for (int k = 0; k < 8; ++k) acc1[k] = fmaf(v1, (float)xv1[k], acc1[k]);
    }
    float accf[8];
    #pragma unroll
    for (int k = 0; k < 8; ++k) accf[k] = acc0[k] + acc1[k];
    #pragma unroll
    for (int off = 8; off < 64; off <<= 1) {
        #pragma unroll
        for (int k = 0; k < 8; ++k) accf[k] += __shfl_xor(accf[k], off);
    }
    if (sub == 0) {
        fx4* t4 = reinterpret_cast<fx4*>(target) + dimq * 2;
        fx4 lo = t4[0], hi = t4[1];
        lo.x += accf[0]; lo.y += accf[1]; lo.z += accf[2]; lo.w += accf[3];
        hi.x += accf[4]; hi.y += accf[5]; hi.z += accf[6]; hi.w += accf[7];
        t4[0] = lo; t4[1] = hi;
    }
}

// ---------- per-layer batch accumulate: fp16 y -> fp32 acc ----------
__global__ void bacc_add_h_kernel(const _Float16* __restrict__ y,
                                  const int* __restrict__ uids, const int* __restrict__ iids,
                                  float* __restrict__ uacc, float* __restrict__ iacc,
                                  int batch, int num_users) {
    int t = blockIdx.x * blockDim.x + threadIdx.x;
    if (t >= batch * 8) return;
    int b = t >> 3;
    int q = t & 7;
    const h8v* y8 = (const h8v*)y;
    h8v u = y8[(long)uids[b] * 8 + q];
    h8v v = y8[((long)num_users + iids[b]) * 8 + q];
    float4* ua = (float4*)uacc + (long)b * 16 + q * 2;
    float4* ia = (float4*)iacc + (long)b * 16 + q * 2;
    float4 a0 = ua[0], a1 = ua[1];
    a0.x += (float)u[0]; a0.y += (float)u[1]; a0.z += (float)u[2]; a0.w += (float)u[3];
    a1.x += (float)u[4]; a1.y += (float)u[5]; a1.z += (float)u[6]; a1.w += (float)u[7];
    ua[0] = a0; ua[1] = a1;
    float4 c0 = ia[0], c1 = ia[1];
    c0.x += (float)v[0]; c0.y += (float)v[1]; c0.z += (float)v[2]; c0.w += (float)v[3];
    c1.x += (float)v[4]; c1.y += (float)v[5]; c1.z += (float)v[6]; c1.w += (float)v[7];
    ia[0] = c0; ia[1] = c1;
}

// ---------- scoring ----------
__global__ void score_kernel(const float* __restrict__ uacc, const float* __restrict__ iacc,
                             float* __restrict__ out, int batch) {
    int lane = threadIdx.x & 63;
    int w = (blockIdx.x * blockDim.x + threadIdx.x) >> 6;
    if (w >= batch) return;
    float p = uacc[(long)w * EMBED_DIM + lane] * iacc[(long)w * EMBED_DIM + lane];
    #pragma unroll
    for (int off = 32; off > 0; off >>= 1) p += __shfl_down(p, off);
    if (lane == 0) out[w] = p * (1.0f / 16.0f);  // (acc/4)·(acc/4)
}

extern "C" void kernel_launch(void* const* d_in, const int* in_sizes, int n_in,
                              void* d_out, int out_size, void* d_ws, size_t ws_size,
                              hipStream_t stream) {
    const float* user_emb = (const float*)d_in[0];
    const float* item_emb = (const float*)d_in[1];
    const int*   adj_rows = (const int*)d_in[2];
    const int*   adj_cols = (const int*)d_in[3];
    const float* adj_vals = (const float*)d_in[4];
    const int*   user_ids = (const int*)d_in[5];
    const int*   item_ids = (const int*)d_in[6];
    float* out = (float*)d_out;

    const int num_users = in_sizes[0] / EMBED_DIM;   // 200000
    const int num_items = in_sizes[1] / EMBED_DIM;   // 100000
    const int n_nodes   = num_users + num_items;     // 300000
    const int nnz       = in_sizes[2];               // 6000000
    const int batch     = in_sizes[5];               // 16384

    const long node_elems = (long)n_nodes * EMBED_DIM;    // 19.2M elems
    const long bacc_elems = (long)batch * EMBED_DIM;      // 1.05M floats

    const int nbuck = (n_nodes + BUCKET_ROWS - 1) >> BUCKET_SHIFT;   // 586
    const int nscan = nbuck * NBLK_A;                                // 150016
    const int nscan_blocks = (nscan + SCAN2_CHUNK - 1) / SCAN2_CHUNK; // 74

    // ---- workspace layout ----
    // xh | bufA | bufB are contiguous fp16 node buffers (38.4 MB each).
    char* wp = (char*)d_ws;
    _Float16* xh   = (_Float16*)wp;      wp += node_elems * sizeof(_Float16);
    _Float16* bufA = (_Float16*)wp;      wp += node_elems * sizeof(_Float16);
    _Float16* bufB = (_Float16*)wp;      wp += node_elems * sizeof(_Float16);
    float* uacc = (float*)wp;            wp += bacc_elems * sizeof(float);
    float* iacc = (float*)wp;            wp += bacc_elems * sizeof(float);
    int*   row_ptr = (int*)wp;           wp += (size_t)(n_nodes + 4) * sizeof(int);
    int*   bsum    = (int*)wp;           wp += 512 * sizeof(int);
    int*   boff    = (int*)wp;           wp += 512 * sizeof(int);
    int*   blockCounts = (int*)wp;       wp += (size_t)nscan * sizeof(int);
    int*   scanOut     = (int*)wp;       wp += (size_t)nscan * sizeof(int);
    wp = (char*)(((uintptr_t)wp + 15) & ~(uintptr_t)15);
    int2*  perm    = (int2*)wp;          wp += (size_t)nnz * sizeof(int2);

    // smeta staging (48 MB) overlays bufA+bufB (76.8 MB contiguous): both are
    // first written by spmm layers, which run after bucket_build consumes smeta.
    int2* smeta = (int2*)bufA;

    const int chunkA = (((nnz + NBLK_A - 1) / NBLK_A) + 1023) & ~1023;   // 24576

    // ---- radix CSR build (no device atomics) ----
    bucket_count_kernel<<<NBLK_A, 256, 0, stream>>>(adj_rows, blockCounts, nnz, nbuck, chunkA);
    scan8_phase1<<<nscan_blocks, 256, 0, stream>>>(blockCounts, bsum, nscan);
    scan_phase2<<<1, 512, 0, stream>>>(bsum, boff, nscan_blocks);
    scan8_phase3<<<nscan_blocks, 256, 0, stream>>>(blockCounts, boff, scanOut, nscan);
    bucket_scatter_kernel<<<NBLK_A, 256, 0, stream>>>(adj_rows, adj_cols, adj_vals,
                                                      scanOut, smeta, nnz, nbuck, chunkA);
    bucket_build_kernel<<<nbuck, 256, 0, stream>>>(smeta, scanOut, perm,
                                                   row_ptr, nnz, n_nodes, nbuck);

    // ---- convert x0 to fp16 (after build: xh is its own region, no overlay) ----
    convert_x_kernel<<<2048, 256, 0, stream>>>(user_emb, item_emb, xh,
                                               num_users * EMBED_DIM, (int)node_elems);

    // ---- batch accumulator init (layer-0 term, fp32) ----
    {
        int blocks = (batch * 16 + 255) / 256;
        init_bacc_kernel<<<blocks, 256, 0, stream>>>(user_emb, item_emb, user_ids, item_ids,
                                                     uacc, iacc, batch);
    }

    const int spmm_blocks = ((n_nodes * 64) + 255) / 256;   // one wave per row
    const int bblocks = (batch * 8 + 255) / 256;

    // ---- layer 1: xh -> bufA ----
    spmm_csr_h_kernel<<<spmm_blocks, 256, 0, stream>>>(row_ptr, perm, xh, bufA, n_nodes);
    bacc_add_h_kernel<<<bblocks, 256, 0, stream>>>(bufA, user_ids, item_ids,
                                                   uacc, iacc, batch, num_users);

    // ---- layer 2: bufA -> bufB ----
    spmm_csr_h_kernel<<<spmm_blocks, 256, 0, stream>>>(row_ptr, perm, bufA, bufB, n_nodes);
    bacc_add_h_kernel<<<bblocks, 256, 0, stream>>>(bufB, user_ids, item_ids,
                                                   uacc, iacc, batch, num_users);

    // ---- layer 3 (batch-restricted): bufB -> uacc/iacc directly ----
    {
        int waves = 2 * batch;                        // 32768 waves
        int blocks = (waves * 64 + 255) / 256;        // 8192 blocks
        spmm_batch_h_kernel<<<blocks, 256, 0, stream>>>(row_ptr, perm, bufB,
                                                        user_ids, item_ids,
                                                        uacc, iacc, batch, num_users);
    }

    // ---- score ----
    {
        int blocks = (batch * 64 + 255) / 256;
        score_kernel<<<blocks, 256, 0, stream>>>(uacc, iacc, out, batch);
    }
}